// Round 3
// baseline (6150.839 us; speedup 1.0000x reference)
//
#include <hip/hip_runtime.h>
#include <hip/hip_bf16.h>

constexpr int Nn  = 32768;   // total nodes
constexpr int Ej  = 294912;  // total edges
constexpr int Bg  = 256;     // graphs
constexpr int EPG = 1152;    // edges per graph
constexpr int QW  = 1092;    // fused qkv row width: q256 k256 v512.. layout below
// qkvr row: [0,256) q | [256,512) k | [512,768) v | [768,1024) r | [1024,1088) skip | [1088,1092) qb

// monotone float<->uint encoding for atomicMax on floats
__device__ __forceinline__ unsigned encf(float f) {
  unsigned u = __float_as_uint(f);
  return (u & 0x80000000u) ? ~u : (u | 0x80000000u);
}
__device__ __forceinline__ float decf(unsigned u) {
  return (u & 0x80000000u) ? __uint_as_float(u & 0x7FFFFFFFu) : __uint_as_float(~u);
}

// 64-lane sum via DPP (VALU pipe, no LDS). Result valid in lane 63.
__device__ __forceinline__ float wave_red_sum(float x) {
  x += __int_as_float(__builtin_amdgcn_update_dpp(0, __float_as_int(x), 0x111, 0xf, 0xf, true)); // row_shr:1
  x += __int_as_float(__builtin_amdgcn_update_dpp(0, __float_as_int(x), 0x112, 0xf, 0xf, true)); // row_shr:2
  x += __int_as_float(__builtin_amdgcn_update_dpp(0, __float_as_int(x), 0x114, 0xf, 0xf, true)); // row_shr:4
  x += __int_as_float(__builtin_amdgcn_update_dpp(0, __float_as_int(x), 0x118, 0xf, 0xf, true)); // row_shr:8
  x += __int_as_float(__builtin_amdgcn_update_dpp(0, __float_as_int(x), 0x142, 0xf, 0xf, true)); // row_bcast:15
  x += __int_as_float(__builtin_amdgcn_update_dpp(0, __float_as_int(x), 0x143, 0xf, 0xf, true)); // row_bcast:31
  return x;
}

// h[n,c] = sum_d x[n,d] * Wn[d,c] + bn[c]   (XD=16)
__global__ void k_node_enc(const float* __restrict__ x, const float* __restrict__ W,
                           const float* __restrict__ b, float* __restrict__ h) {
  int tid = blockIdx.x * 256 + threadIdx.x;  // Nn*64
  int n = tid >> 6, c = tid & 63;
  float acc = b[c];
#pragma unroll
  for (int d = 0; d < 16; ++d)
    acc += x[n * 16 + d] * W[d * 64 + c];
  h[tid] = acc;
}

// e_emb[e,c] = sum_d ea[e,d] * W[d,c] + b[c]   (ED=8), row-major
__global__ void k_edge_enc(const float* __restrict__ ea, const float* __restrict__ W,
                           const float* __restrict__ b, float* __restrict__ e_emb) {
  int tid = blockIdx.x * 256 + threadIdx.x;  // Ej*64
  int e = tid >> 6, c = tid & 63;
  float acc = b[c];
#pragma unroll
  for (int d = 0; d < 8; ++d)
    acc += ea[e * 8 + d] * W[d * 64 + c];
  e_emb[tid] = acc;
}

// Build concatenated weights Wcat[l][64][1092] and bias bcat[l][1092].
// cols 768..1023: M[k][h*64+d] = sum_c Wq[l][k][h*64+c]*We[l][d][h*64+c]  (r = h@M)
// cols 1088..1091: wqb[k][h]   = sum_c Wq[l][k][h*64+c]*be[l][h*64+c]    (qb = h@wqb)
__global__ void k_prep(const float* __restrict__ Wq, const float* __restrict__ bq,
                       const float* __restrict__ Wk, const float* __restrict__ bk,
                       const float* __restrict__ Wv, const float* __restrict__ bv,
                       const float* __restrict__ We, const float* __restrict__ be,
                       const float* __restrict__ Wskip, const float* __restrict__ bskip,
                       float* __restrict__ Wcat, float* __restrict__ bcat) {
  int tid = blockIdx.x * 256 + threadIdx.x;  // 4*64*1092
  int l = tid / (64 * QW);
  int rem = tid % (64 * QW);
  int k = rem / QW, col = rem % QW;
  float w, bias;
  if (col < 256) {
    w = Wq[l * 16384 + k * 256 + col]; bias = bq[l * 256 + col];
  } else if (col < 512) {
    int j = col - 256; w = Wk[l * 16384 + k * 256 + j]; bias = bk[l * 256 + j];
  } else if (col < 768) {
    int j = col - 512; w = Wv[l * 16384 + k * 256 + j]; bias = bv[l * 256 + j];
  } else if (col < 1024) {
    int j = col - 768; int hh = j >> 6, d = j & 63;
    float acc = 0.f, bacc = 0.f;
#pragma unroll 8
    for (int c = 0; c < 64; ++c) {
      float we = We[l * 16384 + d * 256 + hh * 64 + c];
      acc += Wq[l * 16384 + k * 256 + hh * 64 + c] * we;
      bacc += bq[l * 256 + hh * 64 + c] * we;
    }
    w = acc; bias = bacc;
  } else if (col < 1088) {
    int j = col - 1024; w = Wskip[l * 4096 + k * 64 + j]; bias = bskip[l * 64 + j];
  } else {
    int hh = col - 1088;
    float acc = 0.f, bacc = 0.f;
#pragma unroll 8
    for (int c = 0; c < 64; ++c) {
      float bev = be[l * 256 + hh * 64 + c];
      acc += Wq[l * 16384 + k * 256 + hh * 64 + c] * bev;
      bacc += bq[l * 256 + hh * 64 + c] * bev;
    }
    w = acc; bias = bacc;
  }
  Wcat[(size_t)l * 64 * QW + k * QW + col] = w;
  if (k == 0) bcat[l * QW + col] = bias;
}

// Fused node GEMM: out[n, 0..1092) = h[n,:] @ Wcat_l + bcat_l
// grid (5, 2048), block 256. Block covers 16 nodes x 256 cols. Thread: 4 nodes x 4 cols.
__global__ void __launch_bounds__(256) k_qkv(const float* __restrict__ h,
                                             const float* __restrict__ Wcat_l,
                                             const float* __restrict__ bcat_l,
                                             float* __restrict__ out) {
  __shared__ float hL[16 * 64];
  int tid = threadIdx.x;
  int n0 = blockIdx.y * 16;
  {
    int n = tid >> 4, c4 = tid & 15;
    *(float4*)&hL[n * 64 + c4 * 4] = *(const float4*)&h[(size_t)(n0 + n) * 64 + c4 * 4];
  }
  __syncthreads();
  int jg = tid & 63, ng = tid >> 6;
  int j4 = blockIdx.x * 256 + jg * 4;
  if (j4 >= QW) return;
  float4 acc0 = {0, 0, 0, 0}, acc1 = {0, 0, 0, 0}, acc2 = {0, 0, 0, 0}, acc3 = {0, 0, 0, 0};
#pragma unroll
  for (int c4 = 0; c4 < 16; ++c4) {
    float4 h0 = *(const float4*)&hL[(ng * 4 + 0) * 64 + c4 * 4];
    float4 h1 = *(const float4*)&hL[(ng * 4 + 1) * 64 + c4 * 4];
    float4 h2 = *(const float4*)&hL[(ng * 4 + 2) * 64 + c4 * 4];
    float4 h3 = *(const float4*)&hL[(ng * 4 + 3) * 64 + c4 * 4];
    const float* hv0 = (const float*)&h0;
    const float* hv1 = (const float*)&h1;
    const float* hv2 = (const float*)&h2;
    const float* hv3 = (const float*)&h3;
#pragma unroll
    for (int cc = 0; cc < 4; ++cc) {
      float4 w = *(const float4*)&Wcat_l[(size_t)(c4 * 4 + cc) * QW + j4];
      acc0.x += hv0[cc] * w.x; acc0.y += hv0[cc] * w.y; acc0.z += hv0[cc] * w.z; acc0.w += hv0[cc] * w.w;
      acc1.x += hv1[cc] * w.x; acc1.y += hv1[cc] * w.y; acc1.z += hv1[cc] * w.z; acc1.w += hv1[cc] * w.w;
      acc2.x += hv2[cc] * w.x; acc2.y += hv2[cc] * w.y; acc2.z += hv2[cc] * w.z; acc2.w += hv2[cc] * w.w;
      acc3.x += hv3[cc] * w.x; acc3.y += hv3[cc] * w.y; acc3.z += hv3[cc] * w.z; acc3.w += hv3[cc] * w.w;
    }
  }
  float4 bb = *(const float4*)&bcat_l[j4];
  acc0.x += bb.x; acc0.y += bb.y; acc0.z += bb.z; acc0.w += bb.w;
  acc1.x += bb.x; acc1.y += bb.y; acc1.z += bb.z; acc1.w += bb.w;
  acc2.x += bb.x; acc2.y += bb.y; acc2.z += bb.z; acc2.w += bb.w;
  acc3.x += bb.x; acc3.y += bb.y; acc3.z += bb.z; acc3.w += bb.w;
  *(float4*)&out[(size_t)(n0 + ng * 4 + 0) * QW + j4] = acc0;
  *(float4*)&out[(size_t)(n0 + ng * 4 + 1) * QW + j4] = acc1;
  *(float4*)&out[(size_t)(n0 + ng * 4 + 2) * QW + j4] = acc2;
  *(float4*)&out[(size_t)(n0 + ng * 4 + 3) * QW + j4] = acc3;
}

// Fused per-(graph,head) attention. Block = (g,h), 256 threads, ~117 KB LDS.
// Writes aggv into qkvr cols [0,256) and t into cols [768,1024) (overwriting q/r), s into sbuf.
constexpr int TS = 66;  // LDS row stride: (66*d+c)%32 = (2d+c)%32 -> <=2-way conflicts (free)
__global__ void __launch_bounds__(256, 1) k_attn(float* __restrict__ qkvr,
                                                 const float* __restrict__ e_emb,
                                                 const int* __restrict__ ei,
                                                 float* __restrict__ sbuf) {
  __shared__ float qL[128 * TS], kL[128 * TS], rL[128 * TS];
  __shared__ float alphaL[EPG];
  __shared__ int srcL[EPG], dstL[EPG];
  __shared__ unsigned mL[128];
  __shared__ float sL[128], qbL[128];
  int g = blockIdx.x, h = blockIdx.y;
  int tid = threadIdx.x;
  float* base = qkvr + (size_t)g * 128 * QW;
  // phase 0: stage q,k,r tiles + qb + edge lists, init m/s
  for (int idx = tid; idx < 128 * 32; idx += 256) {
    int n = idx >> 5, c2 = idx & 31;
    const float* row = base + n * QW + h * 64 + c2 * 2;
    *(float2*)&qL[n * TS + c2 * 2] = *(const float2*)(row);
    *(float2*)&kL[n * TS + c2 * 2] = *(const float2*)(row + 256);
    *(float2*)&rL[n * TS + c2 * 2] = *(const float2*)(row + 768);
  }
  if (tid < 128) {
    qbL[tid] = base[tid * QW + 1088 + h];
    mL[tid] = 0u;
    sL[tid] = 0.f;
  }
  for (int idx = tid; idx < EPG; idx += 256) {
    srcL[idx] = ei[g * EPG + idx] - g * 128;
    dstL[idx] = ei[Ej + g * EPG + idx] - g * 128;
  }
  __syncthreads();
  int wave = tid >> 6, lane = tid & 63;
  // phase 1: alpha per edge (c-per-lane, DPP reduce), LDS atomicMax for segment max
  const float* eb = e_emb + (size_t)g * EPG * 64 + lane;
#pragma unroll 2
  for (int e = wave * (EPG / 4); e < (wave + 1) * (EPG / 4); ++e) {
    int src = srcL[e], dst = dstL[e];
    float part = qL[dst * TS + lane] * kL[src * TS + lane] + eb[e * 64] * rL[dst * TS + lane];
    float sum = wave_red_sum(part);
    if (lane == 63) {
      float a = 0.125f * (sum + qbL[dst]);
      alphaL[e] = a;
      atomicMax(&mL[dst], encf(a));
    }
  }
  __syncthreads();
  // phase 2: exp + segment sum; concurrently stage v into qL and zero aggv(kL)/t(rL)
  for (int idx = tid; idx < 128 * 32; idx += 256) {
    int n = idx >> 5, c2 = idx & 31;
    *(float2*)&qL[n * TS + c2 * 2] = *(const float2*)(base + n * QW + 512 + h * 64 + c2 * 2);
    *(float2*)&kL[n * TS + c2 * 2] = make_float2(0.f, 0.f);
    *(float2*)&rL[n * TS + c2 * 2] = make_float2(0.f, 0.f);
  }
  for (int e = tid; e < EPG; e += 256) {
    float m = decf(mL[dstL[e]]);
    float ex = expf(alphaL[e] - m);
    alphaL[e] = ex;
    atomicAdd(&sL[dstL[e]], ex);
  }
  __syncthreads();
  // phase 3: aggv[dst] += w*v[src]; t[dst] += w*e_emb  (c-per-lane, conflict-free LDS atomics)
#pragma unroll 2
  for (int e = wave * (EPG / 4); e < (wave + 1) * (EPG / 4); ++e) {
    int src = srcL[e], dst = dstL[e];
    float w = alphaL[e] / fmaxf(sL[dst], 1e-16f);
    atomicAdd(&kL[dst * TS + lane], w * qL[src * TS + lane]);
    atomicAdd(&rL[dst * TS + lane], w * eb[e * 64]);
  }
  __syncthreads();
  // writeback (owned, no global atomics)
  for (int idx = tid; idx < 128 * 32; idx += 256) {
    int n = idx >> 5, c2 = idx & 31;
    float* row = base + n * QW + h * 64 + c2 * 2;
    *(float2*)(row) = *(const float2*)&kL[n * TS + c2 * 2];
    *(float2*)(row + 768) = *(const float2*)&rL[n * TS + c2 * 2];
  }
  if (tid < 128) sbuf[(g * 128 + tid) * 4 + h] = sL[tid];
}

// out[n,c] = 0.25*sum_h( aggv + t@We_h + (s>0)*be ) + sk; stash virtual rows; h += out
__global__ void k_update(const float* __restrict__ qkvr, const float* __restrict__ s,
                         const float* __restrict__ We_l, const float* __restrict__ be_l,
                         float* h, float* __restrict__ vemb, int layer) {
  int tid = blockIdx.x * 256 + threadIdx.x;  // Nn*64
  int n = tid >> 6, c = tid & 63;
  const float* row = qkvr + (size_t)n * QW;
  float acc = 0.f;
#pragma unroll
  for (int hh = 0; hh < 4; ++hh) {
    float sw = (s[n * 4 + hh] > 0.f) ? 1.f : 0.f;
    float a = row[hh * 64 + c] + sw * be_l[hh * 64 + c];
    const float* tr = row + 768 + hh * 64;
    const float* w = We_l + hh * 64 + c;
#pragma unroll 8
    for (int d = 0; d < 64; ++d)
      a += tr[d] * w[d * 256];
    acc += a;
  }
  float outv = acc * 0.25f + row[1024 + c];
  if ((n & 127) == 127)
    vemb[(n >> 7) * 256 + layer * 64 + c] = outv;
  h[tid] = outv + h[tid];
}

// pool = vemb @ W_down + b_down; out = sigmoid(pool @ W_out + b_out)
__global__ void k_head(const float* __restrict__ vemb, const float* __restrict__ Wd,
                       const float* __restrict__ bd, const float* __restrict__ Wo,
                       const float* __restrict__ bo, float* __restrict__ out) {
  int g = blockIdx.x;
  int c = threadIdx.x;  // 64 threads
  const float* vr = vemb + g * 256;
  float acc = bd[c];
#pragma unroll 16
  for (int j = 0; j < 256; ++j)
    acc += vr[j] * Wd[j * 64 + c];
  float p = acc * Wo[c];
#pragma unroll
  for (int off = 32; off; off >>= 1) p += __shfl_down(p, off);
  if (c == 0) {
    float logit = p + bo[0];
    out[g] = 1.f / (1.f + expf(-logit));
  }
}

extern "C" void kernel_launch(void* const* d_in, const int* in_sizes, int n_in,
                              void* d_out, int out_size, void* d_ws, size_t ws_size,
                              hipStream_t stream) {
  const float* x         = (const float*)d_in[0];
  const float* edge_attr = (const float*)d_in[1];
  const int*   ei        = (const int*)d_in[2];
  const float* W_node = (const float*)d_in[4];
  const float* b_node = (const float*)d_in[5];
  const float* W_edge = (const float*)d_in[6];
  const float* b_edge = (const float*)d_in[7];
  const float* Wq = (const float*)d_in[8];
  const float* bq = (const float*)d_in[9];
  const float* Wk = (const float*)d_in[10];
  const float* bk = (const float*)d_in[11];
  const float* Wv = (const float*)d_in[12];
  const float* bv = (const float*)d_in[13];
  const float* We = (const float*)d_in[14];
  const float* be = (const float*)d_in[15];
  const float* Wskip = (const float*)d_in[16];
  const float* bskip = (const float*)d_in[17];
  const float* W_down = (const float*)d_in[18];
  const float* b_down = (const float*)d_in[19];
  const float* W_out  = (const float*)d_in[20];
  const float* b_out  = (const float*)d_in[21];
  float* out = (float*)d_out;

  // workspace carve (fp32): ~229 MiB total
  float* p = (float*)d_ws;
  float* hbuf  = p; p += (size_t)Nn * 64;       //   8.4 MB
  float* e_emb = p; p += (size_t)Ej * 64;       //  75.5 MB
  float* qkvr  = p; p += (size_t)Nn * QW;       // 143.1 MB
  float* sbuf  = p; p += (size_t)Nn * 4;
  float* Wcat  = p; p += (size_t)4 * 64 * QW;
  float* bcat  = p; p += (size_t)4 * QW;
  float* vemb  = p; p += (size_t)Bg * 256;

  k_prep<<<4 * 64 * QW / 256, 256, 0, stream>>>(Wq, bq, Wk, bk, Wv, bv, We, be,
                                                Wskip, bskip, Wcat, bcat);
  k_node_enc<<<Nn * 64 / 256, 256, 0, stream>>>(x, W_node, b_node, hbuf);
  k_edge_enc<<<Ej * 64 / 256, 256, 0, stream>>>(edge_attr, W_edge, b_edge, e_emb);

  for (int i = 0; i < 4; ++i) {
    k_qkv<<<dim3(5, Nn / 16), 256, 0, stream>>>(hbuf, Wcat + (size_t)i * 64 * QW,
                                                bcat + i * QW, qkvr);
    k_attn<<<dim3(Bg, 4), 256, 0, stream>>>(qkvr, e_emb, ei, sbuf);
    k_update<<<Nn * 64 / 256, 256, 0, stream>>>(qkvr, sbuf, We + i * 16384,
                                                be + i * 256, hbuf, vemb, i);
  }
  k_head<<<Bg, 64, 0, stream>>>(vemb, W_down, b_down, W_out, b_out, out);
}

// Round 4
// 4652.288 us; speedup vs baseline: 1.3221x; 1.3221x over previous
//
#include <hip/hip_runtime.h>
#include <hip/hip_bf16.h>

constexpr int Nn  = 32768;   // total nodes
constexpr int Ej  = 294912;  // total edges
constexpr int Bg  = 256;     // graphs
constexpr int EPG = 1152;    // edges per graph
constexpr int QW  = 1092;    // logical fused row width
constexpr int QWP = 1104;    // padded row stride: 4416 B = 69 * 64 B (cacheline-aligned rows)
// qkvr row: [0,256) q | [256,512) k | [512,768) v | [768,1024) r | [1024,1088) skip | [1088,1092) qb

// monotone float<->uint encoding for atomicMax on floats
__device__ __forceinline__ unsigned encf(float f) {
  unsigned u = __float_as_uint(f);
  return (u & 0x80000000u) ? ~u : (u | 0x80000000u);
}
__device__ __forceinline__ float decf(unsigned u) {
  return (u & 0x80000000u) ? __uint_as_float(u & 0x7FFFFFFFu) : __uint_as_float(~u);
}

// 64-lane sum via DPP (VALU pipe, no LDS). Result valid in lane 63.
__device__ __forceinline__ float wave_red_sum(float x) {
  x += __int_as_float(__builtin_amdgcn_update_dpp(0, __float_as_int(x), 0x111, 0xf, 0xf, true)); // row_shr:1
  x += __int_as_float(__builtin_amdgcn_update_dpp(0, __float_as_int(x), 0x112, 0xf, 0xf, true)); // row_shr:2
  x += __int_as_float(__builtin_amdgcn_update_dpp(0, __float_as_int(x), 0x114, 0xf, 0xf, true)); // row_shr:4
  x += __int_as_float(__builtin_amdgcn_update_dpp(0, __float_as_int(x), 0x118, 0xf, 0xf, true)); // row_shr:8
  x += __int_as_float(__builtin_amdgcn_update_dpp(0, __float_as_int(x), 0x142, 0xf, 0xf, true)); // row_bcast:15
  x += __int_as_float(__builtin_amdgcn_update_dpp(0, __float_as_int(x), 0x143, 0xf, 0xf, true)); // row_bcast:31
  return x;
}

// h[n,c] = sum_d x[n,d] * Wn[d,c] + bn[c]   (XD=16)
__global__ void k_node_enc(const float* __restrict__ x, const float* __restrict__ W,
                           const float* __restrict__ b, float* __restrict__ h) {
  int tid = blockIdx.x * 256 + threadIdx.x;  // Nn*64
  int n = tid >> 6, c = tid & 63;
  float acc = b[c];
#pragma unroll
  for (int d = 0; d < 16; ++d)
    acc += x[n * 16 + d] * W[d * 64 + c];
  h[tid] = acc;
}

// e_emb[e,c] = sum_d ea[e,d] * W[d,c] + b[c]   (ED=8), row-major
__global__ void k_edge_enc(const float* __restrict__ ea, const float* __restrict__ W,
                           const float* __restrict__ b, float* __restrict__ e_emb) {
  int tid = blockIdx.x * 256 + threadIdx.x;  // Ej*64
  int e = tid >> 6, c = tid & 63;
  float acc = b[c];
#pragma unroll
  for (int d = 0; d < 8; ++d)
    acc += ea[e * 8 + d] * W[d * 64 + c];
  e_emb[tid] = acc;
}

// Build concatenated weights Wcat[l][64][QWP] and bias bcat[l][QW].
__global__ void k_prep(const float* __restrict__ Wq, const float* __restrict__ bq,
                       const float* __restrict__ Wk, const float* __restrict__ bk,
                       const float* __restrict__ Wv, const float* __restrict__ bv,
                       const float* __restrict__ We, const float* __restrict__ be,
                       const float* __restrict__ Wskip, const float* __restrict__ bskip,
                       float* __restrict__ Wcat, float* __restrict__ bcat) {
  int tid = blockIdx.x * 256 + threadIdx.x;  // 4*64*QW
  if (tid >= 4 * 64 * QW) return;
  int l = tid / (64 * QW);
  int rem = tid % (64 * QW);
  int k = rem / QW, col = rem % QW;
  float w, bias;
  if (col < 256) {
    w = Wq[l * 16384 + k * 256 + col]; bias = bq[l * 256 + col];
  } else if (col < 512) {
    int j = col - 256; w = Wk[l * 16384 + k * 256 + j]; bias = bk[l * 256 + j];
  } else if (col < 768) {
    int j = col - 512; w = Wv[l * 16384 + k * 256 + j]; bias = bv[l * 256 + j];
  } else if (col < 1024) {
    int j = col - 768; int hh = j >> 6, d = j & 63;
    float acc = 0.f, bacc = 0.f;
#pragma unroll 8
    for (int c = 0; c < 64; ++c) {
      float we = We[l * 16384 + d * 256 + hh * 64 + c];
      acc += Wq[l * 16384 + k * 256 + hh * 64 + c] * we;
      bacc += bq[l * 256 + hh * 64 + c] * we;
    }
    w = acc; bias = bacc;
  } else if (col < 1088) {
    int j = col - 1024; w = Wskip[l * 4096 + k * 64 + j]; bias = bskip[l * 64 + j];
  } else {
    int hh = col - 1088;
    float acc = 0.f, bacc = 0.f;
#pragma unroll 8
    for (int c = 0; c < 64; ++c) {
      float bev = be[l * 256 + hh * 64 + c];
      acc += Wq[l * 16384 + k * 256 + hh * 64 + c] * bev;
      bacc += bq[l * 256 + hh * 64 + c] * bev;
    }
    w = acc; bias = bacc;
  }
  Wcat[(size_t)l * 64 * QWP + k * QWP + col] = w;
  if (k == 0) bcat[l * QW + col] = bias;
}

// Fused node GEMM: out[n, 0..QW) = h[n,:] @ Wcat_l + bcat_l   (row stride QWP)
// grid (5, 2048), block 256. Block covers 16 nodes x 256 cols. Thread: 4 nodes x 4 cols.
__global__ void __launch_bounds__(256) k_qkv(const float* __restrict__ h,
                                             const float* __restrict__ Wcat_l,
                                             const float* __restrict__ bcat_l,
                                             float* __restrict__ out) {
  __shared__ float hL[16 * 64];
  int tid = threadIdx.x;
  int n0 = blockIdx.y * 16;
  {
    int n = tid >> 4, c4 = tid & 15;
    *(float4*)&hL[n * 64 + c4 * 4] = *(const float4*)&h[(size_t)(n0 + n) * 64 + c4 * 4];
  }
  __syncthreads();
  int jg = tid & 63, ng = tid >> 6;
  int j4 = blockIdx.x * 256 + jg * 4;
  if (j4 >= QW) return;
  float4 acc0 = {0, 0, 0, 0}, acc1 = {0, 0, 0, 0}, acc2 = {0, 0, 0, 0}, acc3 = {0, 0, 0, 0};
#pragma unroll
  for (int c4 = 0; c4 < 16; ++c4) {
    float4 h0 = *(const float4*)&hL[(ng * 4 + 0) * 64 + c4 * 4];
    float4 h1 = *(const float4*)&hL[(ng * 4 + 1) * 64 + c4 * 4];
    float4 h2 = *(const float4*)&hL[(ng * 4 + 2) * 64 + c4 * 4];
    float4 h3 = *(const float4*)&hL[(ng * 4 + 3) * 64 + c4 * 4];
    const float* hv0 = (const float*)&h0;
    const float* hv1 = (const float*)&h1;
    const float* hv2 = (const float*)&h2;
    const float* hv3 = (const float*)&h3;
#pragma unroll
    for (int cc = 0; cc < 4; ++cc) {
      float4 w = *(const float4*)&Wcat_l[(size_t)(c4 * 4 + cc) * QWP + j4];
      acc0.x += hv0[cc] * w.x; acc0.y += hv0[cc] * w.y; acc0.z += hv0[cc] * w.z; acc0.w += hv0[cc] * w.w;
      acc1.x += hv1[cc] * w.x; acc1.y += hv1[cc] * w.y; acc1.z += hv1[cc] * w.z; acc1.w += hv1[cc] * w.w;
      acc2.x += hv2[cc] * w.x; acc2.y += hv2[cc] * w.y; acc2.z += hv2[cc] * w.z; acc2.w += hv2[cc] * w.w;
      acc3.x += hv3[cc] * w.x; acc3.y += hv3[cc] * w.y; acc3.z += hv3[cc] * w.z; acc3.w += hv3[cc] * w.w;
    }
  }
  float4 bb = *(const float4*)&bcat_l[j4];
  acc0.x += bb.x; acc0.y += bb.y; acc0.z += bb.z; acc0.w += bb.w;
  acc1.x += bb.x; acc1.y += bb.y; acc1.z += bb.z; acc1.w += bb.w;
  acc2.x += bb.x; acc2.y += bb.y; acc2.z += bb.z; acc2.w += bb.w;
  acc3.x += bb.x; acc3.y += bb.y; acc3.z += bb.z; acc3.w += bb.w;
  *(float4*)&out[(size_t)(n0 + ng * 4 + 0) * QWP + j4] = acc0;
  *(float4*)&out[(size_t)(n0 + ng * 4 + 1) * QWP + j4] = acc1;
  *(float4*)&out[(size_t)(n0 + ng * 4 + 2) * QWP + j4] = acc2;
  *(float4*)&out[(size_t)(n0 + ng * 4 + 3) * QWP + j4] = acc3;
}

// Fused per-(graph,head) attention. Block = (g,h), 1024 threads (16 waves), ~106 KB LDS.
// Writes aggv into qkvr cols [0,256) and t into cols [768,1024) (overwriting q/r), s into sbuf.
__global__ void __launch_bounds__(1024, 4) k_attn(float* __restrict__ qkvr,
                                                  const float* __restrict__ e_emb,
                                                  const int* __restrict__ ei,
                                                  float* __restrict__ sbuf) {
  __shared__ float qL[128 * 64], kL[128 * 64], rL[128 * 64];
  __shared__ float alphaL[EPG];
  __shared__ int edL[EPG];  // src | dst<<16
  __shared__ unsigned mL[128];
  __shared__ float sL[128], qbL[128];
  int g = blockIdx.x, h = blockIdx.y;
  int tid = threadIdx.x;
  float* base = qkvr + (size_t)g * 128 * QWP;
  // phase 0: stage q,k,r tiles + qb + edge lists, init m/s
  for (int idx = tid; idx < 128 * 16; idx += 1024) {
    int n = idx >> 4, c4 = idx & 15;
    const float* row = base + n * QWP + h * 64 + c4 * 4;
    *(float4*)&qL[n * 64 + c4 * 4] = *(const float4*)(row);
    *(float4*)&kL[n * 64 + c4 * 4] = *(const float4*)(row + 256);
    *(float4*)&rL[n * 64 + c4 * 4] = *(const float4*)(row + 768);
  }
  if (tid < 128) {
    qbL[tid] = base[tid * QWP + 1088 + h];
    mL[tid] = 0u;
    sL[tid] = 0.f;
  }
  for (int idx = tid; idx < EPG; idx += 1024) {
    int s = ei[g * EPG + idx] - g * 128;
    int d = ei[Ej + g * EPG + idx] - g * 128;
    edL[idx] = s | (d << 16);
  }
  __syncthreads();
  int wave = tid >> 6, lane = tid & 63;
  const float* eb = e_emb + (size_t)g * EPG * 64 + lane;
  // phase 1: alpha per edge (c-per-lane, DPP reduce), LDS atomicMax for segment max
#pragma unroll 4
  for (int e = wave * (EPG / 16); e < (wave + 1) * (EPG / 16); ++e) {
    int ed = edL[e];
    int src = ed & 0xffff, dst = ed >> 16;
    float part = qL[dst * 64 + lane] * kL[src * 64 + lane] + eb[(size_t)e * 64] * rL[dst * 64 + lane];
    float sum = wave_red_sum(part);
    if (lane == 63) {
      float a = 0.125f * (sum + qbL[dst]);
      alphaL[e] = a;
      atomicMax(&mL[dst], encf(a));
    }
  }
  __syncthreads();
  // phase 2: stage v into qL, zero aggv(kL)/t(rL); exp + segment sum
  for (int idx = tid; idx < 128 * 16; idx += 1024) {
    int n = idx >> 4, c4 = idx & 15;
    *(float4*)&qL[n * 64 + c4 * 4] = *(const float4*)(base + n * QWP + 512 + h * 64 + c4 * 4);
    *(float4*)&kL[n * 64 + c4 * 4] = make_float4(0.f, 0.f, 0.f, 0.f);
    *(float4*)&rL[n * 64 + c4 * 4] = make_float4(0.f, 0.f, 0.f, 0.f);
  }
  for (int e = tid; e < EPG; e += 1024) {
    int dst = edL[e] >> 16;
    float ex = expf(alphaL[e] - decf(mL[dst]));
    alphaL[e] = ex;
    atomicAdd(&sL[dst], ex);
  }
  __syncthreads();
  // phase 3: aggv[dst] += w*v[src]; t[dst] += w*e_emb  (c-per-lane LDS atomics)
#pragma unroll 4
  for (int e = wave * (EPG / 16); e < (wave + 1) * (EPG / 16); ++e) {
    int ed = edL[e];
    int src = ed & 0xffff, dst = ed >> 16;
    float w = alphaL[e] / fmaxf(sL[dst], 1e-16f);
    atomicAdd(&kL[dst * 64 + lane], w * qL[src * 64 + lane]);
    atomicAdd(&rL[dst * 64 + lane], w * eb[(size_t)e * 64]);
  }
  __syncthreads();
  // writeback (owned, no global atomics)
  for (int idx = tid; idx < 128 * 16; idx += 1024) {
    int n = idx >> 4, c4 = idx & 15;
    float* row = base + n * QWP + h * 64 + c4 * 4;
    *(float4*)(row) = *(const float4*)&kL[n * 64 + c4 * 4];
    *(float4*)(row + 768) = *(const float4*)&rL[n * 64 + c4 * 4];
  }
  if (tid < 128) sbuf[(g * 128 + tid) * 4 + h] = sL[tid];
}

// out[n,c] = 0.25*sum_h( aggv + t@We_h + (s>0)*be ) + sk; stash virtual rows; h += out
__global__ void k_update(const float* __restrict__ qkvr, const float* __restrict__ s,
                         const float* __restrict__ We_l, const float* __restrict__ be_l,
                         float* h, float* __restrict__ vemb, int layer) {
  int tid = blockIdx.x * 256 + threadIdx.x;  // Nn*64
  int n = tid >> 6, c = tid & 63;
  const float* row = qkvr + (size_t)n * QWP;
  float acc = 0.f;
#pragma unroll
  for (int hh = 0; hh < 4; ++hh) {
    float sw = (s[n * 4 + hh] > 0.f) ? 1.f : 0.f;
    float a = row[hh * 64 + c] + sw * be_l[hh * 64 + c];
    const float* tr = row + 768 + hh * 64;
    const float* w = We_l + hh * 64 + c;
#pragma unroll 8
    for (int d = 0; d < 64; ++d)
      a += tr[d] * w[d * 256];
    acc += a;
  }
  float outv = acc * 0.25f + row[1024 + c];
  if ((n & 127) == 127)
    vemb[(n >> 7) * 256 + layer * 64 + c] = outv;
  h[tid] = outv + h[tid];
}

// pool = vemb @ W_down + b_down; out = sigmoid(pool @ W_out + b_out)
__global__ void k_head(const float* __restrict__ vemb, const float* __restrict__ Wd,
                       const float* __restrict__ bd, const float* __restrict__ Wo,
                       const float* __restrict__ bo, float* __restrict__ out) {
  int g = blockIdx.x;
  int c = threadIdx.x;  // 64 threads
  const float* vr = vemb + g * 256;
  float acc = bd[c];
#pragma unroll 16
  for (int j = 0; j < 256; ++j)
    acc += vr[j] * Wd[j * 64 + c];
  float p = acc * Wo[c];
#pragma unroll
  for (int off = 32; off; off >>= 1) p += __shfl_down(p, off);
  if (c == 0) {
    float logit = p + bo[0];
    out[g] = 1.f / (1.f + expf(-logit));
  }
}

extern "C" void kernel_launch(void* const* d_in, const int* in_sizes, int n_in,
                              void* d_out, int out_size, void* d_ws, size_t ws_size,
                              hipStream_t stream) {
  const float* x         = (const float*)d_in[0];
  const float* edge_attr = (const float*)d_in[1];
  const int*   ei        = (const int*)d_in[2];
  const float* W_node = (const float*)d_in[4];
  const float* b_node = (const float*)d_in[5];
  const float* W_edge = (const float*)d_in[6];
  const float* b_edge = (const float*)d_in[7];
  const float* Wq = (const float*)d_in[8];
  const float* bq = (const float*)d_in[9];
  const float* Wk = (const float*)d_in[10];
  const float* bk = (const float*)d_in[11];
  const float* Wv = (const float*)d_in[12];
  const float* bv = (const float*)d_in[13];
  const float* We = (const float*)d_in[14];
  const float* be = (const float*)d_in[15];
  const float* Wskip = (const float*)d_in[16];
  const float* bskip = (const float*)d_in[17];
  const float* W_down = (const float*)d_in[18];
  const float* b_down = (const float*)d_in[19];
  const float* W_out  = (const float*)d_in[20];
  const float* b_out  = (const float*)d_in[21];
  float* out = (float*)d_out;

  // workspace carve (fp32): ~231 MiB total
  float* p = (float*)d_ws;
  float* hbuf  = p; p += (size_t)Nn * 64;        //   8.4 MB
  float* e_emb = p; p += (size_t)Ej * 64;        //  75.5 MB
  float* qkvr  = p; p += (size_t)Nn * QWP;       // 144.7 MB
  float* sbuf  = p; p += (size_t)Nn * 4;
  float* Wcat  = p; p += (size_t)4 * 64 * QWP;
  float* bcat  = p; p += (size_t)4 * QW;
  float* vemb  = p; p += (size_t)Bg * 256;

  k_prep<<<(4 * 64 * QW + 255) / 256, 256, 0, stream>>>(Wq, bq, Wk, bk, Wv, bv, We, be,
                                                        Wskip, bskip, Wcat, bcat);
  k_node_enc<<<Nn * 64 / 256, 256, 0, stream>>>(x, W_node, b_node, hbuf);
  k_edge_enc<<<Ej * 64 / 256, 256, 0, stream>>>(edge_attr, W_edge, b_edge, e_emb);

  for (int i = 0; i < 4; ++i) {
    k_qkv<<<dim3(5, Nn / 16), 256, 0, stream>>>(hbuf, Wcat + (size_t)i * 64 * QWP,
                                                bcat + i * QW, qkvr);
    k_attn<<<dim3(Bg, 4), 1024, 0, stream>>>(qkvr, e_emb, ei, sbuf);
    k_update<<<Nn * 64 / 256, 256, 0, stream>>>(qkvr, sbuf, We + i * 16384,
                                                be + i * 256, hbuf, vemb, i);
  }
  k_head<<<Bg, 64, 0, stream>>>(vemb, W_down, b_down, W_out, b_out, out);
}

// Round 5
// 2858.041 us; speedup vs baseline: 2.1521x; 1.6278x over previous
//
#include <hip/hip_runtime.h>
#include <hip/hip_bf16.h>

constexpr int Nn  = 32768;   // total nodes
constexpr int Ej  = 294912;  // total edges
constexpr int Bg  = 256;     // graphs
constexpr int EPG = 1152;    // edges per graph
constexpr int QW2  = 868;    // fused row: q256 | k256 | v256 | r8:32 | skip64 | qb4
constexpr int QWP2 = 880;    // padded row stride: 3520 B = 55 * 64 B
// col map: [0,256) q(pre-scaled 0.125) | [256,512) k | [512,768) v | [768,800) r8 | [800,864) skip | [864,868) qb'

// monotone float<->uint encoding for atomicMax on floats
__device__ __forceinline__ unsigned encf(float f) {
  unsigned u = __float_as_uint(f);
  return (u & 0x80000000u) ? ~u : (u | 0x80000000u);
}
__device__ __forceinline__ float decf(unsigned u) {
  return (u & 0x80000000u) ? __uint_as_float(u & 0x7FFFFFFFu) : __uint_as_float(~u);
}

// 64-lane sum via DPP (VALU pipe). Result valid in lane 63.
__device__ __forceinline__ float wave_red_sum(float x) {
  x += __int_as_float(__builtin_amdgcn_update_dpp(0, __float_as_int(x), 0x111, 0xf, 0xf, true)); // row_shr:1
  x += __int_as_float(__builtin_amdgcn_update_dpp(0, __float_as_int(x), 0x112, 0xf, 0xf, true)); // row_shr:2
  x += __int_as_float(__builtin_amdgcn_update_dpp(0, __float_as_int(x), 0x114, 0xf, 0xf, true)); // row_shr:4
  x += __int_as_float(__builtin_amdgcn_update_dpp(0, __float_as_int(x), 0x118, 0xf, 0xf, true)); // row_shr:8
  x += __int_as_float(__builtin_amdgcn_update_dpp(0, __float_as_int(x), 0x142, 0xf, 0xf, true)); // row_bcast:15
  x += __int_as_float(__builtin_amdgcn_update_dpp(0, __float_as_int(x), 0x143, 0xf, 0xf, true)); // row_bcast:31
  return x;
}

// h[n,c] = sum_d x[n,d] * Wn[d,c] + bn[c]   (XD=16)
__global__ void k_node_enc(const float* __restrict__ x, const float* __restrict__ W,
                           const float* __restrict__ b, float* __restrict__ h) {
  int tid = blockIdx.x * 256 + threadIdx.x;  // Nn*64
  int n = tid >> 6, c = tid & 63;
  float acc = b[c];
#pragma unroll
  for (int d = 0; d < 16; ++d)
    acc += x[n * 16 + d] * W[d * 64 + c];
  h[tid] = acc;
}

// Build concatenated weights Wcat[l][64][QWP2] and bias bcat[l][QW2].
// M[k][h,d] = sum_c Wq[k][h64+c]*We[d][h64+c]  (r = h@M); r8 = r@W_edge^T; qb' = q.be + r.b_edge
__global__ void k_prep(const float* __restrict__ Wq, const float* __restrict__ bq,
                       const float* __restrict__ Wk, const float* __restrict__ bk,
                       const float* __restrict__ Wv, const float* __restrict__ bv,
                       const float* __restrict__ We, const float* __restrict__ be,
                       const float* __restrict__ Wskip, const float* __restrict__ bskip,
                       const float* __restrict__ W_edge, const float* __restrict__ b_edge,
                       float* __restrict__ Wcat, float* __restrict__ bcat) {
  int tid = blockIdx.x * 256 + threadIdx.x;  // 4*64*QW2
  if (tid >= 4 * 64 * QW2) return;
  int l = tid / (64 * QW2);
  int rem = tid % (64 * QW2);
  int k = rem / QW2, col = rem % QW2;
  const float* Wq_l = Wq + l * 16384;
  const float* We_l = We + l * 16384;
  float w, bias;
  if (col < 256) {
    w = 0.125f * Wq_l[k * 256 + col]; bias = 0.125f * bq[l * 256 + col];
  } else if (col < 512) {
    int j = col - 256; w = Wk[l * 16384 + k * 256 + j]; bias = bk[l * 256 + j];
  } else if (col < 768) {
    int j = col - 512; w = Wv[l * 16384 + k * 256 + j]; bias = bv[l * 256 + j];
  } else if (col < 800) {
    int j = col - 768; int hh = j >> 3, a = j & 7;
    float acc = 0.f, bacc = 0.f;
    for (int d = 0; d < 64; ++d) {
      float m = 0.f, bm = 0.f;
#pragma unroll 8
      for (int c = 0; c < 64; ++c) {
        float we = We_l[d * 256 + hh * 64 + c];
        m += Wq_l[k * 256 + hh * 64 + c] * we;
        bm += bq[l * 256 + hh * 64 + c] * we;
      }
      float wed = W_edge[a * 64 + d];
      acc += m * wed; bacc += bm * wed;
    }
    w = 0.125f * acc; bias = 0.125f * bacc;
  } else if (col < 864) {
    int j = col - 800; w = Wskip[l * 4096 + k * 64 + j]; bias = bskip[l * 64 + j];
  } else {
    int hh = col - 864;
    float acc = 0.f, bacc = 0.f;
    for (int d = 0; d < 64; ++d) {
      float m = 0.f, bm = 0.f;
#pragma unroll 8
      for (int c = 0; c < 64; ++c) {
        float we = We_l[d * 256 + hh * 64 + c];
        m += Wq_l[k * 256 + hh * 64 + c] * we;
        bm += bq[l * 256 + hh * 64 + c] * we;
      }
      acc += m * b_edge[d]; bacc += bm * b_edge[d];
    }
#pragma unroll 8
    for (int c = 0; c < 64; ++c) {
      acc += Wq_l[k * 256 + hh * 64 + c] * be[l * 256 + hh * 64 + c];
      bacc += bq[l * 256 + hh * 64 + c] * be[l * 256 + hh * 64 + c];
    }
    w = 0.125f * acc; bias = 0.125f * bacc;
  }
  Wcat[(size_t)l * 64 * QWP2 + k * QWP2 + col] = w;
  if (k == 0) bcat[l * QW2 + col] = bias;
}

// G[l][h][a][c] = sum_d W_edge[a,d]*We_l[d][h64+c];  bb[l][h][c] = be + b_edge@We
__global__ void k_prep2(const float* __restrict__ We, const float* __restrict__ be,
                        const float* __restrict__ W_edge, const float* __restrict__ b_edge,
                        float* __restrict__ G, float* __restrict__ bb) {
  int tid = blockIdx.x * 256 + threadIdx.x;  // 8192 + 1024
  if (tid < 8192) {
    int l = tid >> 11, rem = tid & 2047;
    int hh = rem >> 9, a = (rem >> 6) & 7, c = rem & 63;
    float acc = 0.f;
#pragma unroll 8
    for (int d = 0; d < 64; ++d)
      acc += W_edge[a * 64 + d] * We[l * 16384 + d * 256 + hh * 64 + c];
    G[tid] = acc;
  } else if (tid < 9216) {
    int t = tid - 8192;
    int l = t >> 8, rem = t & 255;
    int hh = rem >> 6, c = rem & 63;
    float acc = be[l * 256 + hh * 64 + c];
#pragma unroll 8
    for (int d = 0; d < 64; ++d)
      acc += b_edge[d] * We[l * 16384 + d * 256 + hh * 64 + c];
    bb[t] = acc;
  }
}

// Fused node GEMM: out[n, 0..QW2) = h[n,:] @ Wcat_l + bcat_l   (row stride QWP2)
// grid (4, 2048), block 256. Block covers 16 nodes x 256 cols. Thread: 4 nodes x 4 cols.
__global__ void __launch_bounds__(256) k_qkv(const float* __restrict__ h,
                                             const float* __restrict__ Wcat_l,
                                             const float* __restrict__ bcat_l,
                                             float* __restrict__ out) {
  __shared__ float hL[16 * 64];
  int tid = threadIdx.x;
  int n0 = blockIdx.y * 16;
  {
    int n = tid >> 4, c4 = tid & 15;
    *(float4*)&hL[n * 64 + c4 * 4] = *(const float4*)&h[(size_t)(n0 + n) * 64 + c4 * 4];
  }
  __syncthreads();
  int jg = tid & 63, ng = tid >> 6;
  int j4 = blockIdx.x * 256 + jg * 4;
  if (j4 >= QW2) return;
  float4 acc0 = {0, 0, 0, 0}, acc1 = {0, 0, 0, 0}, acc2 = {0, 0, 0, 0}, acc3 = {0, 0, 0, 0};
#pragma unroll
  for (int c4 = 0; c4 < 16; ++c4) {
    float4 h0 = *(const float4*)&hL[(ng * 4 + 0) * 64 + c4 * 4];
    float4 h1 = *(const float4*)&hL[(ng * 4 + 1) * 64 + c4 * 4];
    float4 h2 = *(const float4*)&hL[(ng * 4 + 2) * 64 + c4 * 4];
    float4 h3 = *(const float4*)&hL[(ng * 4 + 3) * 64 + c4 * 4];
    const float* hv0 = (const float*)&h0;
    const float* hv1 = (const float*)&h1;
    const float* hv2 = (const float*)&h2;
    const float* hv3 = (const float*)&h3;
#pragma unroll
    for (int cc = 0; cc < 4; ++cc) {
      float4 w = *(const float4*)&Wcat_l[(size_t)(c4 * 4 + cc) * QWP2 + j4];
      acc0.x += hv0[cc] * w.x; acc0.y += hv0[cc] * w.y; acc0.z += hv0[cc] * w.z; acc0.w += hv0[cc] * w.w;
      acc1.x += hv1[cc] * w.x; acc1.y += hv1[cc] * w.y; acc1.z += hv1[cc] * w.z; acc1.w += hv1[cc] * w.w;
      acc2.x += hv2[cc] * w.x; acc2.y += hv2[cc] * w.y; acc2.z += hv2[cc] * w.z; acc2.w += hv2[cc] * w.w;
      acc3.x += hv3[cc] * w.x; acc3.y += hv3[cc] * w.y; acc3.z += hv3[cc] * w.z; acc3.w += hv3[cc] * w.w;
    }
  }
  float4 bb = *(const float4*)&bcat_l[j4];
  acc0.x += bb.x; acc0.y += bb.y; acc0.z += bb.z; acc0.w += bb.w;
  acc1.x += bb.x; acc1.y += bb.y; acc1.z += bb.z; acc1.w += bb.w;
  acc2.x += bb.x; acc2.y += bb.y; acc2.z += bb.z; acc2.w += bb.w;
  acc3.x += bb.x; acc3.y += bb.y; acc3.z += bb.z; acc3.w += bb.w;
  *(float4*)&out[(size_t)(n0 + ng * 4 + 0) * QWP2 + j4] = acc0;
  *(float4*)&out[(size_t)(n0 + ng * 4 + 1) * QWP2 + j4] = acc1;
  *(float4*)&out[(size_t)(n0 + ng * 4 + 2) * QWP2 + j4] = acc2;
  *(float4*)&out[(size_t)(n0 + ng * 4 + 3) * QWP2 + j4] = acc3;
}

// Fused per-(graph,head) attention. Block = (g,h), 1024 threads (16 waves), ~150.5 KB LDS.
// NO global memory in the edge loops: edge_attr (8 floats/edge) staged in LDS.
// Writes aggv into cols [0,256), t8 into cols [768,800), s into sbuf.
__global__ void __launch_bounds__(1024, 4) k_attn(float* __restrict__ qkvr,
                                                  const float* __restrict__ edge_attr,
                                                  const int* __restrict__ ei,
                                                  float* __restrict__ sbuf) {
  __shared__ float qL[128 * 64];   // q -> aggv
  __shared__ float kL[128 * 64];
  __shared__ float vL[128 * 64];
  __shared__ float eaL[EPG * 8];
  __shared__ float alphaL[EPG];
  __shared__ int edL[EPG];         // src | dst<<16
  __shared__ float r8L[128 * 8], t8L[128 * 8];
  __shared__ unsigned mL[128];
  __shared__ float sL[128], qbL[128];
  int g = blockIdx.x, h = blockIdx.y;
  int tid = threadIdx.x;
  float* base = qkvr + (size_t)g * 128 * QWP2;
  // phase 0: stage q,k,v,r8,qb + edge_attr + edge list; zero m/s/t8
  for (int idx = tid; idx < 128 * 16; idx += 1024) {
    int n = idx >> 4, c4 = idx & 15;
    const float* row = base + n * QWP2 + h * 64 + c4 * 4;
    *(float4*)&qL[n * 64 + c4 * 4] = *(const float4*)(row);
    *(float4*)&kL[n * 64 + c4 * 4] = *(const float4*)(row + 256);
    *(float4*)&vL[n * 64 + c4 * 4] = *(const float4*)(row + 512);
  }
  if (tid < 256) {  // r8: 128 nodes x 2 float4
    int n = tid >> 1, p = tid & 1;
    *(float4*)&r8L[n * 8 + p * 4] = *(const float4*)(base + n * QWP2 + 768 + h * 8 + p * 4);
  }
  if (tid >= 256 && tid < 384) {
    int n = tid - 256;
    qbL[n] = base[n * QWP2 + 864 + h];
    mL[n] = 0u;
    sL[n] = 0.f;
  }
  if (tid >= 384 && tid < 640) {  // zero t8L
    int t = tid - 384;
    *(float4*)&t8L[t * 4] = make_float4(0.f, 0.f, 0.f, 0.f);
  }
  for (int idx = tid; idx < EPG * 2; idx += 1024) {  // edge_attr tile: 2304 float4
    *(float4*)&eaL[idx * 4] = *(const float4*)&edge_attr[(size_t)g * EPG * 8 + idx * 4];
  }
  for (int idx = tid; idx < EPG; idx += 1024) {
    int s = ei[g * EPG + idx] - g * 128;
    int d = ei[Ej + g * EPG + idx] - g * 128;
    edL[idx] = s | (d << 16);
  }
  __syncthreads();
  int wave = tid >> 6, lane = tid & 63;
  // phase 1: alpha per edge (c-per-lane, DPP reduce), LDS atomicMax for segment max
#pragma unroll 4
  for (int e = wave * (EPG / 16); e < (wave + 1) * (EPG / 16); ++e) {
    int ed = edL[e];
    int src = ed & 0xffff, dst = ed >> 16;
    float part = qL[dst * 64 + lane] * kL[src * 64 + lane];
    if (lane < 8) part += eaL[e * 8 + lane] * r8L[dst * 8 + lane];
    float sum = wave_red_sum(part);
    if (lane == 63) {
      float a = sum + qbL[dst];  // 0.125 pre-folded into q/r8/qb weights
      alphaL[e] = a;
      atomicMax(&mL[dst], encf(a));
    }
  }
  __syncthreads();
  // phase 2: zero aggv (qL); exp + segment sum
  for (int idx = tid; idx < 128 * 16; idx += 1024) {
    *(float4*)&qL[idx * 4] = make_float4(0.f, 0.f, 0.f, 0.f);
  }
  for (int e = tid; e < EPG; e += 1024) {
    int dst = edL[e] >> 16;
    float ex = expf(alphaL[e] - decf(mL[dst]));
    alphaL[e] = ex;
    atomicAdd(&sL[dst], ex);
  }
  __syncthreads();
  // phase 3: aggv[dst] += w*v[src]; t8[dst] += w*ea[e]  (LDS atomics only)
#pragma unroll 4
  for (int e = wave * (EPG / 16); e < (wave + 1) * (EPG / 16); ++e) {
    int ed = edL[e];
    int src = ed & 0xffff, dst = ed >> 16;
    float w = alphaL[e] / fmaxf(sL[dst], 1e-16f);
    atomicAdd(&qL[dst * 64 + lane], w * vL[src * 64 + lane]);
    if (lane < 8) atomicAdd(&t8L[dst * 8 + lane], w * eaL[e * 8 + lane]);
  }
  __syncthreads();
  // writeback (owned, no global atomics)
  for (int idx = tid; idx < 128 * 16; idx += 1024) {
    int n = idx >> 4, c4 = idx & 15;
    *(float4*)(base + n * QWP2 + h * 64 + c4 * 4) = *(const float4*)&qL[n * 64 + c4 * 4];
  }
  if (tid < 256) {
    int n = tid >> 1, p = tid & 1;
    *(float4*)(base + n * QWP2 + 768 + h * 8 + p * 4) = *(const float4*)&t8L[n * 8 + p * 4];
  }
  if (tid >= 256 && tid < 384) {
    int n = tid - 256;
    sbuf[(g * 128 + n) * 4 + h] = sL[n];
  }
}

// out[n,c] = 0.25*sum_h( aggv + t8@G_h + (s>0)*bb_h ) + sk; stash virtual rows; h += out
__global__ void k_update(const float* __restrict__ qkvr, const float* __restrict__ s,
                         const float* __restrict__ G_l, const float* __restrict__ bb_l,
                         float* h, float* __restrict__ vemb, int layer) {
  int tid = blockIdx.x * 256 + threadIdx.x;  // Nn*64
  int n = tid >> 6, c = tid & 63;
  const float* row = qkvr + (size_t)n * QWP2;
  float acc = 0.f;
#pragma unroll
  for (int hh = 0; hh < 4; ++hh) {
    float sw = (s[n * 4 + hh] > 0.f) ? 1.f : 0.f;
    float a = row[hh * 64 + c] + sw * bb_l[hh * 64 + c];
#pragma unroll
    for (int a8 = 0; a8 < 8; ++a8)
      a += row[768 + hh * 8 + a8] * G_l[(hh * 8 + a8) * 64 + c];
    acc += a;
  }
  float outv = acc * 0.25f + row[800 + c];
  if ((n & 127) == 127)
    vemb[(n >> 7) * 256 + layer * 64 + c] = outv;
  h[tid] = outv + h[tid];
}

// pool = vemb @ W_down + b_down; out = sigmoid(pool @ W_out + b_out)
__global__ void k_head(const float* __restrict__ vemb, const float* __restrict__ Wd,
                       const float* __restrict__ bd, const float* __restrict__ Wo,
                       const float* __restrict__ bo, float* __restrict__ out) {
  int g = blockIdx.x;
  int c = threadIdx.x;  // 64 threads
  const float* vr = vemb + g * 256;
  float acc = bd[c];
#pragma unroll 16
  for (int j = 0; j < 256; ++j)
    acc += vr[j] * Wd[j * 64 + c];
  float p = acc * Wo[c];
#pragma unroll
  for (int off = 32; off; off >>= 1) p += __shfl_down(p, off);
  if (c == 0) {
    float logit = p + bo[0];
    out[g] = 1.f / (1.f + expf(-logit));
  }
}

extern "C" void kernel_launch(void* const* d_in, const int* in_sizes, int n_in,
                              void* d_out, int out_size, void* d_ws, size_t ws_size,
                              hipStream_t stream) {
  const float* x         = (const float*)d_in[0];
  const float* edge_attr = (const float*)d_in[1];
  const int*   ei        = (const int*)d_in[2];
  const float* W_node = (const float*)d_in[4];
  const float* b_node = (const float*)d_in[5];
  const float* W_edge = (const float*)d_in[6];
  const float* b_edge = (const float*)d_in[7];
  const float* Wq = (const float*)d_in[8];
  const float* bq = (const float*)d_in[9];
  const float* Wk = (const float*)d_in[10];
  const float* bk = (const float*)d_in[11];
  const float* Wv = (const float*)d_in[12];
  const float* bv = (const float*)d_in[13];
  const float* We = (const float*)d_in[14];
  const float* be = (const float*)d_in[15];
  const float* Wskip = (const float*)d_in[16];
  const float* bskip = (const float*)d_in[17];
  const float* W_down = (const float*)d_in[18];
  const float* b_down = (const float*)d_in[19];
  const float* W_out  = (const float*)d_in[20];
  const float* b_out  = (const float*)d_in[21];
  float* out = (float*)d_out;

  // workspace carve (fp32): ~125 MiB total
  float* p = (float*)d_ws;
  float* hbuf  = p; p += (size_t)Nn * 64;        //   8.4 MB
  float* qkvr  = p; p += (size_t)Nn * QWP2;      // 115.3 MB
  float* sbuf  = p; p += (size_t)Nn * 4;
  float* Wcat  = p; p += (size_t)4 * 64 * QWP2;
  float* bcat  = p; p += (size_t)4 * QW2;
  float* Gbuf  = p; p += (size_t)4 * 4 * 8 * 64;
  float* bbuf  = p; p += (size_t)4 * 4 * 64;
  float* vemb  = p; p += (size_t)Bg * 256;

  k_prep<<<(4 * 64 * QW2 + 255) / 256, 256, 0, stream>>>(Wq, bq, Wk, bk, Wv, bv, We, be,
                                                         Wskip, bskip, W_edge, b_edge,
                                                         Wcat, bcat);
  k_prep2<<<36, 256, 0, stream>>>(We, be, W_edge, b_edge, Gbuf, bbuf);
  k_node_enc<<<Nn * 64 / 256, 256, 0, stream>>>(x, W_node, b_node, hbuf);

  for (int i = 0; i < 4; ++i) {
    k_qkv<<<dim3(4, Nn / 16), 256, 0, stream>>>(hbuf, Wcat + (size_t)i * 64 * QWP2,
                                                bcat + i * QW2, qkvr);
    k_attn<<<dim3(Bg, 4), 1024, 0, stream>>>(qkvr, edge_attr, ei, sbuf);
    k_update<<<Nn * 64 / 256, 256, 0, stream>>>(qkvr, sbuf, Gbuf + i * 2048,
                                                bbuf + i * 256, hbuf, vemb, i);
  }
  k_head<<<Bg, 64, 0, stream>>>(vemb, W_down, b_down, W_out, b_out, out);
}

// Round 6
// 1229.155 us; speedup vs baseline: 5.0041x; 2.3252x over previous
//
#include <hip/hip_runtime.h>
#include <hip/hip_bf16.h>

constexpr int Nn  = 32768;   // total nodes
constexpr int Ej  = 294912;  // total edges
constexpr int Bg  = 256;     // graphs
constexpr int EPG = 1152;    // edges per graph
constexpr int QW2  = 868;    // fused row: q256 | k256 | v256 | r8:32 | skip64 | qb4
constexpr int QWP2 = 880;    // padded row stride: 3520 B = 55 * 64 B
constexpr int SP   = 132;    // S/Wmat LDS row stride (floats)
// col map: [0,256) q(pre-scaled 0.125) | [256,512) k | [512,768) v | [768,800) r8 | [800,864) skip | [864,868) qb'

// monotone float<->uint encoding for atomicMax on floats
__device__ __forceinline__ unsigned encf(float f) {
  unsigned u = __float_as_uint(f);
  return (u & 0x80000000u) ? ~u : (u | 0x80000000u);
}
__device__ __forceinline__ float decf(unsigned u) {
  return (u & 0x80000000u) ? __uint_as_float(u & 0x7FFFFFFFu) : __uint_as_float(~u);
}

// h[n,c] = sum_d x[n,d] * Wn[d,c] + bn[c]   (XD=16)
__global__ void k_node_enc(const float* __restrict__ x, const float* __restrict__ W,
                           const float* __restrict__ b, float* __restrict__ h) {
  int tid = blockIdx.x * 256 + threadIdx.x;  // Nn*64
  int n = tid >> 6, c = tid & 63;
  float acc = b[c];
#pragma unroll
  for (int d = 0; d < 16; ++d)
    acc += x[n * 16 + d] * W[d * 64 + c];
  h[tid] = acc;
}

// Build concatenated weights Wcat[l][64][QWP2] and bias bcat[l][QW2].
__global__ void k_prep(const float* __restrict__ Wq, const float* __restrict__ bq,
                       const float* __restrict__ Wk, const float* __restrict__ bk,
                       const float* __restrict__ Wv, const float* __restrict__ bv,
                       const float* __restrict__ We, const float* __restrict__ be,
                       const float* __restrict__ Wskip, const float* __restrict__ bskip,
                       const float* __restrict__ W_edge, const float* __restrict__ b_edge,
                       float* __restrict__ Wcat, float* __restrict__ bcat) {
  int tid = blockIdx.x * 256 + threadIdx.x;  // 4*64*QW2
  if (tid >= 4 * 64 * QW2) return;
  int l = tid / (64 * QW2);
  int rem = tid % (64 * QW2);
  int k = rem / QW2, col = rem % QW2;
  const float* Wq_l = Wq + l * 16384;
  const float* We_l = We + l * 16384;
  float w, bias;
  if (col < 256) {
    w = 0.125f * Wq_l[k * 256 + col]; bias = 0.125f * bq[l * 256 + col];
  } else if (col < 512) {
    int j = col - 256; w = Wk[l * 16384 + k * 256 + j]; bias = bk[l * 256 + j];
  } else if (col < 768) {
    int j = col - 512; w = Wv[l * 16384 + k * 256 + j]; bias = bv[l * 256 + j];
  } else if (col < 800) {
    int j = col - 768; int hh = j >> 3, a = j & 7;
    float acc = 0.f, bacc = 0.f;
    for (int d = 0; d < 64; ++d) {
      float m = 0.f, bm = 0.f;
#pragma unroll 8
      for (int c = 0; c < 64; ++c) {
        float we = We_l[d * 256 + hh * 64 + c];
        m += Wq_l[k * 256 + hh * 64 + c] * we;
        bm += bq[l * 256 + hh * 64 + c] * we;
      }
      float wed = W_edge[a * 64 + d];
      acc += m * wed; bacc += bm * wed;
    }
    w = 0.125f * acc; bias = 0.125f * bacc;
  } else if (col < 864) {
    int j = col - 800; w = Wskip[l * 4096 + k * 64 + j]; bias = bskip[l * 64 + j];
  } else {
    int hh = col - 864;
    float acc = 0.f, bacc = 0.f;
    for (int d = 0; d < 64; ++d) {
      float m = 0.f, bm = 0.f;
#pragma unroll 8
      for (int c = 0; c < 64; ++c) {
        float we = We_l[d * 256 + hh * 64 + c];
        m += Wq_l[k * 256 + hh * 64 + c] * we;
        bm += bq[l * 256 + hh * 64 + c] * we;
      }
      acc += m * b_edge[d]; bacc += bm * b_edge[d];
    }
#pragma unroll 8
    for (int c = 0; c < 64; ++c) {
      acc += Wq_l[k * 256 + hh * 64 + c] * be[l * 256 + hh * 64 + c];
      bacc += bq[l * 256 + hh * 64 + c] * be[l * 256 + hh * 64 + c];
    }
    w = 0.125f * acc; bias = 0.125f * bacc;
  }
  Wcat[(size_t)l * 64 * QWP2 + k * QWP2 + col] = w;
  if (k == 0) bcat[l * QW2 + col] = bias;
}

// G[l][h][a][c] = sum_d W_edge[a,d]*We_l[d][h64+c];  bb[l][h][c] = be + b_edge@We
__global__ void k_prep2(const float* __restrict__ We, const float* __restrict__ be,
                        const float* __restrict__ W_edge, const float* __restrict__ b_edge,
                        float* __restrict__ G, float* __restrict__ bb) {
  int tid = blockIdx.x * 256 + threadIdx.x;  // 8192 + 1024
  if (tid < 8192) {
    int l = tid >> 11, rem = tid & 2047;
    int hh = rem >> 9, a = (rem >> 6) & 7, c = rem & 63;
    float acc = 0.f;
#pragma unroll 8
    for (int d = 0; d < 64; ++d)
      acc += W_edge[a * 64 + d] * We[l * 16384 + d * 256 + hh * 64 + c];
    G[tid] = acc;
  } else if (tid < 9216) {
    int t = tid - 8192;
    int l = t >> 8, rem = t & 255;
    int hh = rem >> 6, c = rem & 63;
    float acc = be[l * 256 + hh * 64 + c];
#pragma unroll 8
    for (int d = 0; d < 64; ++d)
      acc += b_edge[d] * We[l * 16384 + d * 256 + hh * 64 + c];
    bb[t] = acc;
  }
}

// Fused node GEMM: out[n, 0..QW2) = h[n,:] @ Wcat_l + bcat_l   (row stride QWP2)
__global__ void __launch_bounds__(256) k_qkv(const float* __restrict__ h,
                                             const float* __restrict__ Wcat_l,
                                             const float* __restrict__ bcat_l,
                                             float* __restrict__ out) {
  __shared__ float hL[16 * 64];
  int tid = threadIdx.x;
  int n0 = blockIdx.y * 16;
  {
    int n = tid >> 4, c4 = tid & 15;
    *(float4*)&hL[n * 64 + c4 * 4] = *(const float4*)&h[(size_t)(n0 + n) * 64 + c4 * 4];
  }
  __syncthreads();
  int jg = tid & 63, ng = tid >> 6;
  int j4 = blockIdx.x * 256 + jg * 4;
  if (j4 >= QW2) return;
  float4 acc0 = {0, 0, 0, 0}, acc1 = {0, 0, 0, 0}, acc2 = {0, 0, 0, 0}, acc3 = {0, 0, 0, 0};
#pragma unroll
  for (int c4 = 0; c4 < 16; ++c4) {
    float4 h0 = *(const float4*)&hL[(ng * 4 + 0) * 64 + c4 * 4];
    float4 h1 = *(const float4*)&hL[(ng * 4 + 1) * 64 + c4 * 4];
    float4 h2 = *(const float4*)&hL[(ng * 4 + 2) * 64 + c4 * 4];
    float4 h3 = *(const float4*)&hL[(ng * 4 + 3) * 64 + c4 * 4];
    const float* hv0 = (const float*)&h0;
    const float* hv1 = (const float*)&h1;
    const float* hv2 = (const float*)&h2;
    const float* hv3 = (const float*)&h3;
#pragma unroll
    for (int cc = 0; cc < 4; ++cc) {
      float4 w = *(const float4*)&Wcat_l[(size_t)(c4 * 4 + cc) * QWP2 + j4];
      acc0.x += hv0[cc] * w.x; acc0.y += hv0[cc] * w.y; acc0.z += hv0[cc] * w.z; acc0.w += hv0[cc] * w.w;
      acc1.x += hv1[cc] * w.x; acc1.y += hv1[cc] * w.y; acc1.z += hv1[cc] * w.z; acc1.w += hv1[cc] * w.w;
      acc2.x += hv2[cc] * w.x; acc2.y += hv2[cc] * w.y; acc2.z += hv2[cc] * w.z; acc2.w += hv2[cc] * w.w;
      acc3.x += hv3[cc] * w.x; acc3.y += hv3[cc] * w.y; acc3.z += hv3[cc] * w.z; acc3.w += hv3[cc] * w.w;
    }
  }
  float4 bb = *(const float4*)&bcat_l[j4];
  acc0.x += bb.x; acc0.y += bb.y; acc0.z += bb.z; acc0.w += bb.w;
  acc1.x += bb.x; acc1.y += bb.y; acc1.z += bb.z; acc1.w += bb.w;
  acc2.x += bb.x; acc2.y += bb.y; acc2.z += bb.z; acc2.w += bb.w;
  acc3.x += bb.x; acc3.y += bb.y; acc3.z += bb.z; acc3.w += bb.w;
  *(float4*)&out[(size_t)(n0 + ng * 4 + 0) * QWP2 + j4] = acc0;
  *(float4*)&out[(size_t)(n0 + ng * 4 + 1) * QWP2 + j4] = acc1;
  *(float4*)&out[(size_t)(n0 + ng * 4 + 2) * QWP2 + j4] = acc2;
  *(float4*)&out[(size_t)(n0 + ng * 4 + 3) * QWP2 + j4] = acc3;
}

// Dense-GEMM attention. Block = (g,h), 512 threads (8 waves), ~148.5 KB LDS.
// P1: S = Q@K^T (128x128x64 tiled GEMM). P2: per-edge alpha from S + ea.r8.
// P3: exp/sum; zero Wmat(=S). P4: scatter softmax weights into Wmat; t8.
// P5: agg = Wmat@V (128x64x128 GEMM) -> global. All fp32.
__global__ void __launch_bounds__(512, 2) k_attn(float* __restrict__ qkvr,
                                                 const float* __restrict__ edge_attr,
                                                 const int* __restrict__ ei,
                                                 float* __restrict__ sbuf) {
  __shared__ float qL[128 * 64];    // Q row-major
  __shared__ float kvL[64 * 128];   // P1: kT[k][src]; P2+: vL[src][c]
  __shared__ float S[128 * SP];     // scores, then Wmat
  __shared__ float alphaL[EPG];
  __shared__ int edL[EPG];          // src | dst<<16
  __shared__ float r8L[128 * 8], t8L[128 * 8];
  __shared__ unsigned mL[128];
  __shared__ float sL[128], qbL[128];
  int g = blockIdx.x, h = blockIdx.y;
  int tid = threadIdx.x;
  float* base = qkvr + (size_t)g * 128 * QWP2;
  const float* eaG = edge_attr + (size_t)g * EPG * 8;

  // ---- P0: stage q (row-major), k (transposed), r8, qb, edges; zero m/s/t8
  for (int idx = tid; idx < 128 * 16; idx += 512) {
    int n = idx >> 4, c4 = idx & 15;
    const float* row = base + n * QWP2 + h * 64 + c4 * 4;
    *(float4*)&qL[n * 64 + c4 * 4] = *(const float4*)(row);
    float4 kv = *(const float4*)(row + 256);
    kvL[(c4 * 4 + 0) * 128 + n] = kv.x;
    kvL[(c4 * 4 + 1) * 128 + n] = kv.y;
    kvL[(c4 * 4 + 2) * 128 + n] = kv.z;
    kvL[(c4 * 4 + 3) * 128 + n] = kv.w;
  }
  if (tid < 256) {
    int n = tid >> 1, pp = tid & 1;
    *(float4*)&r8L[n * 8 + pp * 4] = *(const float4*)(base + n * QWP2 + 768 + h * 8 + pp * 4);
  } else if (tid < 384) {
    int n = tid - 256;
    qbL[n] = base[n * QWP2 + 864 + h];
    mL[n] = 0u;
    sL[n] = 0.f;
  }
  for (int idx = tid; idx < 256; idx += 512)
    *(float4*)&t8L[idx * 4] = make_float4(0.f, 0.f, 0.f, 0.f);
  for (int idx = tid; idx < EPG; idx += 512) {
    int s = ei[g * EPG + idx] - g * 128;
    int d = ei[Ej + g * EPG + idx] - g * 128;
    edL[idx] = s | (d << 16);
  }
  __syncthreads();

  // ---- P1: S[d][s] = sum_k q[d][k]*k[s][k].  8x4 register tile per thread.
  {
    int td = tid >> 5, ts = tid & 31;
    int dst0 = td * 8, src0 = ts * 4;
    float acc[8][4] = {};
#pragma unroll 2
    for (int k0 = 0; k0 < 64; k0 += 4) {
      float4 kv[4];
#pragma unroll
      for (int kk = 0; kk < 4; ++kk) kv[kk] = *(const float4*)&kvL[(k0 + kk) * 128 + src0];
#pragma unroll
      for (int i = 0; i < 8; ++i) {
        float4 qv = *(const float4*)&qL[(dst0 + i) * 64 + k0];
#pragma unroll
        for (int j = 0; j < 4; ++j) {
          const float* kvp = (const float*)kv;
          acc[i][j] += qv.x * kvp[0 * 4 + j] + qv.y * kvp[1 * 4 + j] +
                       qv.z * kvp[2 * 4 + j] + qv.w * kvp[3 * 4 + j];
        }
      }
    }
#pragma unroll
    for (int i = 0; i < 8; ++i)
      *(float4*)&S[(dst0 + i) * SP + src0] = *(float4*)&acc[i][0];
  }
  __syncthreads();

  // ---- P2: stage v (over kT); per-edge alpha = S[dst][src] + ea.r8 + qb; seg max
  for (int idx = tid; idx < 128 * 16; idx += 512) {
    int n = idx >> 4, c4 = idx & 15;
    *(float4*)&kvL[n * 64 + c4 * 4] = *(const float4*)(base + n * QWP2 + 512 + h * 64 + c4 * 4);
  }
  for (int e = tid; e < EPG; e += 512) {
    int ed = edL[e];
    int src = ed & 0xffff, dst = ed >> 16;
    float4 ea0 = *(const float4*)(eaG + (size_t)e * 8);
    float4 ea1 = *(const float4*)(eaG + (size_t)e * 8 + 4);
    const float* r8 = &r8L[dst * 8];
    float a = S[dst * SP + src] + qbL[dst]
            + ea0.x * r8[0] + ea0.y * r8[1] + ea0.z * r8[2] + ea0.w * r8[3]
            + ea1.x * r8[4] + ea1.y * r8[5] + ea1.z * r8[6] + ea1.w * r8[7];
    alphaL[e] = a;
    atomicMax(&mL[dst], encf(a));
  }
  __syncthreads();

  // ---- P3: exp + segment sum; zero Wmat (=S region)
  for (int idx = tid; idx < 128 * (SP / 4); idx += 512)
    *(float4*)&S[idx * 4] = make_float4(0.f, 0.f, 0.f, 0.f);
  for (int e = tid; e < EPG; e += 512) {
    int dst = edL[e] >> 16;
    float ex = expf(alphaL[e] - decf(mL[dst]));
    alphaL[e] = ex;
    atomicAdd(&sL[dst], ex);
  }
  __syncthreads();

  // ---- P4: scatter normalized weights into Wmat; accumulate t8
  for (int e = tid; e < EPG; e += 512) {
    int ed = edL[e];
    int src = ed & 0xffff, dst = ed >> 16;
    float w = alphaL[e] / fmaxf(sL[dst], 1e-16f);
    atomicAdd(&S[dst * SP + src], w);
    float4 ea0 = *(const float4*)(eaG + (size_t)e * 8);
    float4 ea1 = *(const float4*)(eaG + (size_t)e * 8 + 4);
    float* t8 = &t8L[dst * 8];
    atomicAdd(t8 + 0, w * ea0.x); atomicAdd(t8 + 1, w * ea0.y);
    atomicAdd(t8 + 2, w * ea0.z); atomicAdd(t8 + 3, w * ea0.w);
    atomicAdd(t8 + 4, w * ea1.x); atomicAdd(t8 + 5, w * ea1.y);
    atomicAdd(t8 + 6, w * ea1.z); atomicAdd(t8 + 7, w * ea1.w);
  }
  __syncthreads();

  // ---- P5: agg[d][c] = sum_s Wmat[d][s]*v[s][c].  4x4 tile per thread. Direct global store.
  {
    int td = tid >> 4, tc = tid & 15;
    int dst0 = td * 4, c0 = tc * 4;
    float acc[4][4] = {};
#pragma unroll 2
    for (int k0 = 0; k0 < 128; k0 += 4) {
      float4 wv[4], vv[4];
#pragma unroll
      for (int i = 0; i < 4; ++i) wv[i] = *(const float4*)&S[(dst0 + i) * SP + k0];
#pragma unroll
      for (int kk = 0; kk < 4; ++kk) vv[kk] = *(const float4*)&kvL[(k0 + kk) * 64 + c0];
      const float* vvp = (const float*)vv;
#pragma unroll
      for (int i = 0; i < 4; ++i) {
        const float* wvp = (const float*)&wv[i];
#pragma unroll
        for (int j = 0; j < 4; ++j)
          acc[i][j] += wvp[0] * vvp[0 * 4 + j] + wvp[1] * vvp[1 * 4 + j] +
                       wvp[2] * vvp[2 * 4 + j] + wvp[3] * vvp[3 * 4 + j];
      }
    }
#pragma unroll
    for (int i = 0; i < 4; ++i)
      *(float4*)(base + (size_t)(dst0 + i) * QWP2 + h * 64 + c0) = *(float4*)&acc[i][0];
  }
  if (tid < 256) {
    int n = tid >> 1, pp = tid & 1;
    *(float4*)(base + n * QWP2 + 768 + h * 8 + pp * 4) = *(const float4*)&t8L[n * 8 + pp * 4];
  } else if (tid < 384) {
    int n = tid - 256;
    sbuf[(g * 128 + n) * 4 + h] = sL[n];
  }
}

// out[n,c] = 0.25*sum_h( aggv + t8@G_h + (s>0)*bb_h ) + sk; stash virtual rows; h += out
__global__ void k_update(const float* __restrict__ qkvr, const float* __restrict__ s,
                         const float* __restrict__ G_l, const float* __restrict__ bb_l,
                         float* h, float* __restrict__ vemb, int layer) {
  int tid = blockIdx.x * 256 + threadIdx.x;  // Nn*64
  int n = tid >> 6, c = tid & 63;
  const float* row = qkvr + (size_t)n * QWP2;
  float acc = 0.f;
#pragma unroll
  for (int hh = 0; hh < 4; ++hh) {
    float sw = (s[n * 4 + hh] > 0.f) ? 1.f : 0.f;
    float a = row[hh * 64 + c] + sw * bb_l[hh * 64 + c];
#pragma unroll
    for (int a8 = 0; a8 < 8; ++a8)
      a += row[768 + hh * 8 + a8] * G_l[(hh * 8 + a8) * 64 + c];
    acc += a;
  }
  float outv = acc * 0.25f + row[800 + c];
  if ((n & 127) == 127)
    vemb[(n >> 7) * 256 + layer * 64 + c] = outv;
  h[tid] = outv + h[tid];
}

// pool = vemb @ W_down + b_down; out = sigmoid(pool @ W_out + b_out)
__global__ void k_head(const float* __restrict__ vemb, const float* __restrict__ Wd,
                       const float* __restrict__ bd, const float* __restrict__ Wo,
                       const float* __restrict__ bo, float* __restrict__ out) {
  int g = blockIdx.x;
  int c = threadIdx.x;  // 64 threads
  const float* vr = vemb + g * 256;
  float acc = bd[c];
#pragma unroll 16
  for (int j = 0; j < 256; ++j)
    acc += vr[j] * Wd[j * 64 + c];
  float p = acc * Wo[c];
#pragma unroll
  for (int off = 32; off; off >>= 1) p += __shfl_down(p, off);
  if (c == 0) {
    float logit = p + bo[0];
    out[g] = 1.f / (1.f + expf(-logit));
  }
}

extern "C" void kernel_launch(void* const* d_in, const int* in_sizes, int n_in,
                              void* d_out, int out_size, void* d_ws, size_t ws_size,
                              hipStream_t stream) {
  const float* x         = (const float*)d_in[0];
  const float* edge_attr = (const float*)d_in[1];
  const int*   ei        = (const int*)d_in[2];
  const float* W_node = (const float*)d_in[4];
  const float* b_node = (const float*)d_in[5];
  const float* W_edge = (const float*)d_in[6];
  const float* b_edge = (const float*)d_in[7];
  const float* Wq = (const float*)d_in[8];
  const float* bq = (const float*)d_in[9];
  const float* Wk = (const float*)d_in[10];
  const float* bk = (const float*)d_in[11];
  const float* Wv = (const float*)d_in[12];
  const float* bv = (const float*)d_in[13];
  const float* We = (const float*)d_in[14];
  const float* be = (const float*)d_in[15];
  const float* Wskip = (const float*)d_in[16];
  const float* bskip = (const float*)d_in[17];
  const float* W_down = (const float*)d_in[18];
  const float* b_down = (const float*)d_in[19];
  const float* W_out  = (const float*)d_in[20];
  const float* b_out  = (const float*)d_in[21];
  float* out = (float*)d_out;

  // workspace carve (fp32): ~125 MiB total
  float* p = (float*)d_ws;
  float* hbuf  = p; p += (size_t)Nn * 64;        //   8.4 MB
  float* qkvr  = p; p += (size_t)Nn * QWP2;      // 115.3 MB
  float* sbuf  = p; p += (size_t)Nn * 4;
  float* Wcat  = p; p += (size_t)4 * 64 * QWP2;
  float* bcat  = p; p += (size_t)4 * QW2;
  float* Gbuf  = p; p += (size_t)4 * 4 * 8 * 64;
  float* bbuf  = p; p += (size_t)4 * 4 * 64;
  float* vemb  = p; p += (size_t)Bg * 256;

  k_prep<<<(4 * 64 * QW2 + 255) / 256, 256, 0, stream>>>(Wq, bq, Wk, bk, Wv, bv, We, be,
                                                         Wskip, bskip, W_edge, b_edge,
                                                         Wcat, bcat);
  k_prep2<<<36, 256, 0, stream>>>(We, be, W_edge, b_edge, Gbuf, bbuf);
  k_node_enc<<<Nn * 64 / 256, 256, 0, stream>>>(x, W_node, b_node, hbuf);

  for (int i = 0; i < 4; ++i) {
    k_qkv<<<dim3(4, Nn / 16), 256, 0, stream>>>(hbuf, Wcat + (size_t)i * 64 * QWP2,
                                                bcat + i * QW2, qkvr);
    k_attn<<<dim3(Bg, 4), 512, 0, stream>>>(qkvr, edge_attr, ei, sbuf);
    k_update<<<Nn * 64 / 256, 256, 0, stream>>>(qkvr, sbuf, Gbuf + i * 2048,
                                                bbuf + i * 256, hbuf, vemb, i);
  }
  k_head<<<Bg, 64, 0, stream>>>(vemb, W_down, b_down, W_out, b_out, out);
}

// Round 7
// 1047.616 us; speedup vs baseline: 5.8713x; 1.1733x over previous
//
#include <hip/hip_runtime.h>
#include <hip/hip_bf16.h>

constexpr int Nn  = 32768;   // total nodes
constexpr int Ej  = 294912;  // total edges
constexpr int Bg  = 256;     // graphs
constexpr int EPG = 1152;    // edges per graph
constexpr int QW2  = 868;    // fused row: q256 | k256 | v256 | r8:32 | skip64 | qb4
constexpr int QWP2 = 880;    // padded row stride: 3520 B = 55 * 64 B
constexpr int SP   = 132;    // S/Wmat fp32 LDS row stride (floats)
constexpr int QS   = 80;     // Q/K bf16 LDS row stride (halfwords) - uniform bank coverage
constexpr int VS   = 136;    // Vt/Wbf bf16 LDS row stride (halfwords)

typedef __attribute__((ext_vector_type(8))) short short8;   // 8 bf16 = 4 VGPRs (MFMA A/B frag)
typedef __attribute__((ext_vector_type(4))) float f32x4;    // MFMA C/D frag

// monotone float<->uint encoding for atomicMax on floats
__device__ __forceinline__ unsigned encf(float f) {
  unsigned u = __float_as_uint(f);
  return (u & 0x80000000u) ? ~u : (u | 0x80000000u);
}
__device__ __forceinline__ float decf(unsigned u) {
  return (u & 0x80000000u) ? __uint_as_float(u & 0x7FFFFFFFu) : __uint_as_float(~u);
}
// fp32 -> bf16 bits, round-to-nearest-even
__device__ __forceinline__ unsigned short f2bf(float f) {
  unsigned u = __float_as_uint(f);
  u += 0x7FFFu + ((u >> 16) & 1u);
  return (unsigned short)(u >> 16);
}

// h[n,c] = sum_d x[n,d] * Wn[d,c] + bn[c]   (XD=16)
__global__ void k_node_enc(const float* __restrict__ x, const float* __restrict__ W,
                           const float* __restrict__ b, float* __restrict__ h) {
  int tid = blockIdx.x * 256 + threadIdx.x;  // Nn*64
  int n = tid >> 6, c = tid & 63;
  float acc = b[c];
#pragma unroll
  for (int d = 0; d < 16; ++d)
    acc += x[n * 16 + d] * W[d * 64 + c];
  h[tid] = acc;
}

// Build concatenated weights Wcat[l][64][QWP2] and bias bcat[l][QW2].
__global__ void k_prep(const float* __restrict__ Wq, const float* __restrict__ bq,
                       const float* __restrict__ Wk, const float* __restrict__ bk,
                       const float* __restrict__ Wv, const float* __restrict__ bv,
                       const float* __restrict__ We, const float* __restrict__ be,
                       const float* __restrict__ Wskip, const float* __restrict__ bskip,
                       const float* __restrict__ W_edge, const float* __restrict__ b_edge,
                       float* __restrict__ Wcat, float* __restrict__ bcat) {
  int tid = blockIdx.x * 256 + threadIdx.x;  // 4*64*QW2
  if (tid >= 4 * 64 * QW2) return;
  int l = tid / (64 * QW2);
  int rem = tid % (64 * QW2);
  int k = rem / QW2, col = rem % QW2;
  const float* Wq_l = Wq + l * 16384;
  const float* We_l = We + l * 16384;
  float w, bias;
  if (col < 256) {
    w = 0.125f * Wq_l[k * 256 + col]; bias = 0.125f * bq[l * 256 + col];
  } else if (col < 512) {
    int j = col - 256; w = Wk[l * 16384 + k * 256 + j]; bias = bk[l * 256 + j];
  } else if (col < 768) {
    int j = col - 512; w = Wv[l * 16384 + k * 256 + j]; bias = bv[l * 256 + j];
  } else if (col < 800) {
    int j = col - 768; int hh = j >> 3, a = j & 7;
    float acc = 0.f, bacc = 0.f;
    for (int d = 0; d < 64; ++d) {
      float m = 0.f, bm = 0.f;
#pragma unroll 8
      for (int c = 0; c < 64; ++c) {
        float we = We_l[d * 256 + hh * 64 + c];
        m += Wq_l[k * 256 + hh * 64 + c] * we;
        bm += bq[l * 256 + hh * 64 + c] * we;
      }
      float wed = W_edge[a * 64 + d];
      acc += m * wed; bacc += bm * wed;
    }
    w = 0.125f * acc; bias = 0.125f * bacc;
  } else if (col < 864) {
    int j = col - 800; w = Wskip[l * 4096 + k * 64 + j]; bias = bskip[l * 64 + j];
  } else {
    int hh = col - 864;
    float acc = 0.f, bacc = 0.f;
    for (int d = 0; d < 64; ++d) {
      float m = 0.f, bm = 0.f;
#pragma unroll 8
      for (int c = 0; c < 64; ++c) {
        float we = We_l[d * 256 + hh * 64 + c];
        m += Wq_l[k * 256 + hh * 64 + c] * we;
        bm += bq[l * 256 + hh * 64 + c] * we;
      }
      acc += m * b_edge[d]; bacc += bm * b_edge[d];
    }
#pragma unroll 8
    for (int c = 0; c < 64; ++c) {
      acc += Wq_l[k * 256 + hh * 64 + c] * be[l * 256 + hh * 64 + c];
      bacc += bq[l * 256 + hh * 64 + c] * be[l * 256 + hh * 64 + c];
    }
    w = 0.125f * acc; bias = 0.125f * bacc;
  }
  Wcat[(size_t)l * 64 * QWP2 + k * QWP2 + col] = w;
  if (k == 0) bcat[l * QW2 + col] = bias;
}

// G[l][h][a][c] = sum_d W_edge[a,d]*We_l[d][h64+c];  bb[l][h][c] = be + b_edge@We
__global__ void k_prep2(const float* __restrict__ We, const float* __restrict__ be,
                        const float* __restrict__ W_edge, const float* __restrict__ b_edge,
                        float* __restrict__ G, float* __restrict__ bb) {
  int tid = blockIdx.x * 256 + threadIdx.x;  // 8192 + 1024
  if (tid < 8192) {
    int l = tid >> 11, rem = tid & 2047;
    int hh = rem >> 9, a = (rem >> 6) & 7, c = rem & 63;
    float acc = 0.f;
#pragma unroll 8
    for (int d = 0; d < 64; ++d)
      acc += W_edge[a * 64 + d] * We[l * 16384 + d * 256 + hh * 64 + c];
    G[tid] = acc;
  } else if (tid < 9216) {
    int t = tid - 8192;
    int l = t >> 8, rem = t & 255;
    int hh = rem >> 6, c = rem & 63;
    float acc = be[l * 256 + hh * 64 + c];
#pragma unroll 8
    for (int d = 0; d < 64; ++d)
      acc += b_edge[d] * We[l * 16384 + d * 256 + hh * 64 + c];
    bb[t] = acc;
  }
}

// Fused node GEMM: out[n, 0..QW2) = h[n,:] @ Wcat_l + bcat_l   (row stride QWP2)
__global__ void __launch_bounds__(256) k_qkv(const float* __restrict__ h,
                                             const float* __restrict__ Wcat_l,
                                             const float* __restrict__ bcat_l,
                                             float* __restrict__ out) {
  __shared__ float hL[16 * 64];
  int tid = threadIdx.x;
  int n0 = blockIdx.y * 16;
  {
    int n = tid >> 4, c4 = tid & 15;
    *(float4*)&hL[n * 64 + c4 * 4] = *(const float4*)&h[(size_t)(n0 + n) * 64 + c4 * 4];
  }
  __syncthreads();
  int jg = tid & 63, ng = tid >> 6;
  int j4 = blockIdx.x * 256 + jg * 4;
  if (j4 >= QW2) return;
  float4 acc0 = {0, 0, 0, 0}, acc1 = {0, 0, 0, 0}, acc2 = {0, 0, 0, 0}, acc3 = {0, 0, 0, 0};
#pragma unroll
  for (int c4 = 0; c4 < 16; ++c4) {
    float4 h0 = *(const float4*)&hL[(ng * 4 + 0) * 64 + c4 * 4];
    float4 h1 = *(const float4*)&hL[(ng * 4 + 1) * 64 + c4 * 4];
    float4 h2 = *(const float4*)&hL[(ng * 4 + 2) * 64 + c4 * 4];
    float4 h3 = *(const float4*)&hL[(ng * 4 + 3) * 64 + c4 * 4];
    const float* hv0 = (const float*)&h0;
    const float* hv1 = (const float*)&h1;
    const float* hv2 = (const float*)&h2;
    const float* hv3 = (const float*)&h3;
#pragma unroll
    for (int cc = 0; cc < 4; ++cc) {
      float4 w = *(const float4*)&Wcat_l[(size_t)(c4 * 4 + cc) * QWP2 + j4];
      acc0.x += hv0[cc] * w.x; acc0.y += hv0[cc] * w.y; acc0.z += hv0[cc] * w.z; acc0.w += hv0[cc] * w.w;
      acc1.x += hv1[cc] * w.x; acc1.y += hv1[cc] * w.y; acc1.z += hv1[cc] * w.z; acc1.w += hv1[cc] * w.w;
      acc2.x += hv2[cc] * w.x; acc2.y += hv2[cc] * w.y; acc2.z += hv2[cc] * w.z; acc2.w += hv2[cc] * w.w;
      acc3.x += hv3[cc] * w.x; acc3.y += hv3[cc] * w.y; acc3.z += hv3[cc] * w.z; acc3.w += hv3[cc] * w.w;
    }
  }
  float4 bb = *(const float4*)&bcat_l[j4];
  acc0.x += bb.x; acc0.y += bb.y; acc0.z += bb.z; acc0.w += bb.w;
  acc1.x += bb.x; acc1.y += bb.y; acc1.z += bb.z; acc1.w += bb.w;
  acc2.x += bb.x; acc2.y += bb.y; acc2.z += bb.z; acc2.w += bb.w;
  acc3.x += bb.x; acc3.y += bb.y; acc3.z += bb.z; acc3.w += bb.w;
  *(float4*)&out[(size_t)(n0 + ng * 4 + 0) * QWP2 + j4] = acc0;
  *(float4*)&out[(size_t)(n0 + ng * 4 + 1) * QWP2 + j4] = acc1;
  *(float4*)&out[(size_t)(n0 + ng * 4 + 2) * QWP2 + j4] = acc2;
  *(float4*)&out[(size_t)(n0 + ng * 4 + 3) * QWP2 + j4] = acc3;
}

// MFMA dense attention. Block = (g,h), 512 threads (8 waves), 128.0 KB LDS.
// P1: S = Q@K^T via mfma_f32_16x16x32_bf16. P2: stage Vt(bf16); per-edge alpha.
// P3: zero S; exp/sum. P4: scatter w (fp32 atomics) + t8. P4.5: repack Wmat->bf16.
// P5: agg = Wmat@V via MFMA -> global.
__global__ void __launch_bounds__(512) k_attn(float* __restrict__ qkvr,
                                              const float* __restrict__ edge_attr,
                                              const int* __restrict__ ei,
                                              float* __restrict__ sbuf) {
  __shared__ unsigned short Qu[128 * QS];   // Q bf16, stride 80
  __shared__ unsigned short KVu[128 * QS];  // P1: K bf16 (stride 80); P2+: Vt bf16 (64 x stride 136)
  __shared__ float S[128 * SP];             // fp32 scores -> Wmat fp32 -> (low) Wmat bf16
  __shared__ float alphaL[EPG];
  __shared__ int edL[EPG];                  // src | dst<<16
  __shared__ float r8L[128 * 8];
  __shared__ float t8L[128 * 9];            // stride 9: spread atomic banks
  __shared__ unsigned mL[128];
  __shared__ float sL[128], qbL[128];
  int g = blockIdx.x, h = blockIdx.y;
  int tid = threadIdx.x;
  int lane = tid & 63, m16 = lane & 15, quad = lane >> 4, wv = tid >> 6;
  float* base = qkvr + (size_t)g * 128 * QWP2;
  const float* eaG = edge_attr + (size_t)g * EPG * 8;

  // ---- P0: stage Q,K as bf16; r8, qb, edges; zero m/s/t8
  for (int idx = tid; idx < 1024; idx += 512) {
    int n = idx >> 3, c8 = idx & 7;
    const float* row = base + n * QWP2 + h * 64 + c8 * 8;
    float4 a0 = *(const float4*)(row), a1 = *(const float4*)(row + 4);
    uint4 qp;
    qp.x = f2bf(a0.x) | ((unsigned)f2bf(a0.y) << 16);
    qp.y = f2bf(a0.z) | ((unsigned)f2bf(a0.w) << 16);
    qp.z = f2bf(a1.x) | ((unsigned)f2bf(a1.y) << 16);
    qp.w = f2bf(a1.z) | ((unsigned)f2bf(a1.w) << 16);
    *(uint4*)&Qu[n * QS + c8 * 8] = qp;
    float4 b0 = *(const float4*)(row + 256), b1 = *(const float4*)(row + 260);
    uint4 kp;
    kp.x = f2bf(b0.x) | ((unsigned)f2bf(b0.y) << 16);
    kp.y = f2bf(b0.z) | ((unsigned)f2bf(b0.w) << 16);
    kp.z = f2bf(b1.x) | ((unsigned)f2bf(b1.y) << 16);
    kp.w = f2bf(b1.z) | ((unsigned)f2bf(b1.w) << 16);
    *(uint4*)&KVu[n * QS + c8 * 8] = kp;
  }
  for (int idx = tid; idx < 256; idx += 512) {
    int n = idx >> 1, pp = idx & 1;
    *(float4*)&r8L[n * 8 + pp * 4] = *(const float4*)(base + n * QWP2 + 768 + h * 8 + pp * 4);
  }
  if (tid < 128) {
    qbL[tid] = base[tid * QWP2 + 864 + h];
    mL[tid] = 0u;
    sL[tid] = 0.f;
  }
  for (int idx = tid; idx < EPG; idx += 512) {
    t8L[idx] = 0.f;
    int s = ei[g * EPG + idx] - g * 128;
    int d = ei[Ej + g * EPG + idx] - g * 128;
    edL[idx] = s | (d << 16);
  }
  __syncthreads();

  // ---- P1: S = Q@K^T.  Wave wv: dst-strip wv*16, all 8 src tiles. K=64 -> 2 mfma/tile.
  {
    int dst0 = wv * 16;
    const short8 a0 = *(const short8*)&Qu[(dst0 + m16) * QS + quad * 8];
    const short8 a1 = *(const short8*)&Qu[(dst0 + m16) * QS + 32 + quad * 8];
#pragma unroll
    for (int st = 0; st < 8; ++st) {
      int src0 = st * 16;
      const short8 b0 = *(const short8*)&KVu[(src0 + m16) * QS + quad * 8];
      const short8 b1 = *(const short8*)&KVu[(src0 + m16) * QS + 32 + quad * 8];
      f32x4 acc = {0.f, 0.f, 0.f, 0.f};
      acc = __builtin_amdgcn_mfma_f32_16x16x32_bf16(a0, b0, acc, 0, 0, 0);
      acc = __builtin_amdgcn_mfma_f32_16x16x32_bf16(a1, b1, acc, 0, 0, 0);
#pragma unroll
      for (int r = 0; r < 4; ++r)
        S[(dst0 + quad * 4 + r) * SP + src0 + m16] = acc[r];
    }
  }
  __syncthreads();

  // ---- P2: stage Vt (bf16, transposed, stride VS); per-edge alpha; segment max
  for (int idx = tid; idx < 1024; idx += 512) {
    int n = idx >> 3, c8 = idx & 7;
    const float* row = base + n * QWP2 + 512 + h * 64 + c8 * 8;
    float4 v0 = *(const float4*)(row), v1 = *(const float4*)(row + 4);
    KVu[(c8 * 8 + 0) * VS + n] = f2bf(v0.x);
    KVu[(c8 * 8 + 1) * VS + n] = f2bf(v0.y);
    KVu[(c8 * 8 + 2) * VS + n] = f2bf(v0.z);
    KVu[(c8 * 8 + 3) * VS + n] = f2bf(v0.w);
    KVu[(c8 * 8 + 4) * VS + n] = f2bf(v1.x);
    KVu[(c8 * 8 + 5) * VS + n] = f2bf(v1.y);
    KVu[(c8 * 8 + 6) * VS + n] = f2bf(v1.z);
    KVu[(c8 * 8 + 7) * VS + n] = f2bf(v1.w);
  }
  for (int e = tid; e < EPG; e += 512) {
    int ed = edL[e];
    int src = ed & 0xffff, dst = ed >> 16;
    float4 ea0 = *(const float4*)(eaG + (size_t)e * 8);
    float4 ea1 = *(const float4*)(eaG + (size_t)e * 8 + 4);
    float4 r80 = *(const float4*)&r8L[dst * 8];
    float4 r81 = *(const float4*)&r8L[dst * 8 + 4];
    float a = S[dst * SP + src] + qbL[dst]
            + ea0.x * r80.x + ea0.y * r80.y + ea0.z * r80.z + ea0.w * r80.w
            + ea1.x * r81.x + ea1.y * r81.y + ea1.z * r81.z + ea1.w * r81.w;
    alphaL[e] = a;
    atomicMax(&mL[dst], encf(a));
  }
  __syncthreads();

  // ---- P3: zero S (whole buffer); exp + segment sum
  for (int idx = tid; idx < 128 * (SP / 4); idx += 512)
    *(float4*)&S[idx * 4] = make_float4(0.f, 0.f, 0.f, 0.f);
  for (int e = tid; e < EPG; e += 512) {
    int dst = edL[e] >> 16;
    float ex = expf(alphaL[e] - decf(mL[dst]));
    alphaL[e] = ex;
    atomicAdd(&sL[dst], ex);
  }
  __syncthreads();

  // ---- P4: scatter normalized weights into Wmat(fp32); accumulate t8 (stride 9)
  for (int e = tid; e < EPG; e += 512) {
    int ed = edL[e];
    int src = ed & 0xffff, dst = ed >> 16;
    float w = alphaL[e] / fmaxf(sL[dst], 1e-16f);
    atomicAdd(&S[dst * SP + src], w);
    float4 ea0 = *(const float4*)(eaG + (size_t)e * 8);
    float4 ea1 = *(const float4*)(eaG + (size_t)e * 8 + 4);
    float* t8 = &t8L[dst * 9];
    atomicAdd(t8 + 0, w * ea0.x); atomicAdd(t8 + 1, w * ea0.y);
    atomicAdd(t8 + 2, w * ea0.z); atomicAdd(t8 + 3, w * ea0.w);
    atomicAdd(t8 + 4, w * ea1.x); atomicAdd(t8 + 5, w * ea1.y);
    atomicAdd(t8 + 6, w * ea1.z); atomicAdd(t8 + 7, w * ea1.w);
  }
  __syncthreads();

  // ---- P4.5: repack Wmat fp32 -> bf16 in place (stride VS), regs + barrier
  {
    float vals[32];
    int i0 = tid * 32;
    int dst = i0 >> 7, src0 = i0 & 127;
#pragma unroll
    for (int i = 0; i < 32; ++i)
      vals[i] = S[dst * SP + src0 + i];
    __syncthreads();
    unsigned short* Wu = (unsigned short*)S;
#pragma unroll
    for (int g4 = 0; g4 < 4; ++g4) {
      uint4 u;
      u.x = f2bf(vals[g4 * 8 + 0]) | ((unsigned)f2bf(vals[g4 * 8 + 1]) << 16);
      u.y = f2bf(vals[g4 * 8 + 2]) | ((unsigned)f2bf(vals[g4 * 8 + 3]) << 16);
      u.z = f2bf(vals[g4 * 8 + 4]) | ((unsigned)f2bf(vals[g4 * 8 + 5]) << 16);
      u.w = f2bf(vals[g4 * 8 + 6]) | ((unsigned)f2bf(vals[g4 * 8 + 7]) << 16);
      *(uint4*)&Wu[dst * VS + src0 + g4 * 8] = u;
    }
  }
  __syncthreads();

  // ---- P5: agg = Wmat(128x128)@V(128x64) via MFMA. Wave wv: dst-strip, 4 c-tiles.
  {
    const unsigned short* Wu = (const unsigned short*)S;
    int dst0 = wv * 16;
    short8 a[4];
#pragma unroll
    for (int ks = 0; ks < 4; ++ks)
      a[ks] = *(const short8*)&Wu[(dst0 + m16) * VS + ks * 32 + quad * 8];
#pragma unroll
    for (int ct = 0; ct < 4; ++ct) {
      int c0 = ct * 16;
      f32x4 acc = {0.f, 0.f, 0.f, 0.f};
#pragma unroll
      for (int ks = 0; ks < 4; ++ks) {
        const short8 b = *(const short8*)&KVu[(c0 + m16) * VS + ks * 32 + quad * 8];
        acc = __builtin_amdgcn_mfma_f32_16x16x32_bf16(a[ks], b, acc, 0, 0, 0);
      }
#pragma unroll
      for (int r = 0; r < 4; ++r)
        base[(size_t)(dst0 + quad * 4 + r) * QWP2 + h * 64 + c0 + m16] = acc[r];
    }
  }
  // t8 + s writeback
  if (tid < 128) {
    float tmp[8];
#pragma unroll
    for (int j = 0; j < 8; ++j) tmp[j] = t8L[tid * 9 + j];
    *(float4*)(base + tid * QWP2 + 768 + h * 8) = make_float4(tmp[0], tmp[1], tmp[2], tmp[3]);
    *(float4*)(base + tid * QWP2 + 768 + h * 8 + 4) = make_float4(tmp[4], tmp[5], tmp[6], tmp[7]);
    sbuf[(g * 128 + tid) * 4 + h] = sL[tid];
  }
}

// out[n,c] = 0.25*sum_h( aggv + t8@G_h + (s>0)*bb_h ) + sk; stash virtual rows; h += out
__global__ void k_update(const float* __restrict__ qkvr, const float* __restrict__ s,
                         const float* __restrict__ G_l, const float* __restrict__ bb_l,
                         float* h, float* __restrict__ vemb, int layer) {
  int tid = blockIdx.x * 256 + threadIdx.x;  // Nn*64
  int n = tid >> 6, c = tid & 63;
  const float* row = qkvr + (size_t)n * QWP2;
  float acc = 0.f;
#pragma unroll
  for (int hh = 0; hh < 4; ++hh) {
    float sw = (s[n * 4 + hh] > 0.f) ? 1.f : 0.f;
    float a = row[hh * 64 + c] + sw * bb_l[hh * 64 + c];
#pragma unroll
    for (int a8 = 0; a8 < 8; ++a8)
      a += row[768 + hh * 8 + a8] * G_l[(hh * 8 + a8) * 64 + c];
    acc += a;
  }
  float outv = acc * 0.25f + row[800 + c];
  if ((n & 127) == 127)
    vemb[(n >> 7) * 256 + layer * 64 + c] = outv;
  h[tid] = outv + h[tid];
}

// pool = vemb @ W_down + b_down; out = sigmoid(pool @ W_out + b_out)
__global__ void k_head(const float* __restrict__ vemb, const float* __restrict__ Wd,
                       const float* __restrict__ bd, const float* __restrict__ Wo,
                       const float* __restrict__ bo, float* __restrict__ out) {
  int g = blockIdx.x;
  int c = threadIdx.x;  // 64 threads
  const float* vr = vemb + g * 256;
  float acc = bd[c];
#pragma unroll 16
  for (int j = 0; j < 256; ++j)
    acc += vr[j] * Wd[j * 64 + c];
  float p = acc * Wo[c];
#pragma unroll
  for (int off = 32; off; off >>= 1) p += __shfl_down(p, off);
  if (c == 0) {
    float logit = p + bo[0];
    out[g] = 1.f / (1.f + expf(-logit));
  }
}

extern "C" void kernel_launch(void* const* d_in, const int* in_sizes, int n_in,
                              void* d_out, int out_size, void* d_ws, size_t ws_size,
                              hipStream_t stream) {
  const float* x         = (const float*)d_in[0];
  const float* edge_attr = (const float*)d_in[1];
  const int*   ei        = (const int*)d_in[2];
  const float* W_node = (const float*)d_in[4];
  const float* b_node = (const float*)d_in[5];
  const float* W_edge = (const float*)d_in[6];
  const float* b_edge = (const float*)d_in[7];
  const float* Wq = (const float*)d_in[8];
  const float* bq = (const float*)d_in[9];
  const float* Wk = (const float*)d_in[10];
  const float* bk = (const float*)d_in[11];
  const float* Wv = (const float*)d_in[12];
  const float* bv = (const float*)d_in[13];
  const float* We = (const float*)d_in[14];
  const float* be = (const float*)d_in[15];
  const float* Wskip = (const float*)d_in[16];
  const float* bskip = (const float*)d_in[17];
  const float* W_down = (const float*)d_in[18];
  const float* b_down = (const float*)d_in[19];
  const float* W_out  = (const float*)d_in[20];
  const float* b_out  = (const float*)d_in[21];
  float* out = (float*)d_out;

  // workspace carve (fp32): ~125 MiB total
  float* p = (float*)d_ws;
  float* hbuf  = p; p += (size_t)Nn * 64;        //   8.4 MB
  float* qkvr  = p; p += (size_t)Nn * QWP2;      // 115.3 MB
  float* sbuf  = p; p += (size_t)Nn * 4;
  float* Wcat  = p; p += (size_t)4 * 64 * QWP2;
  float* bcat  = p; p += (size_t)4 * QW2;
  float* Gbuf  = p; p += (size_t)4 * 4 * 8 * 64;
  float* bbuf  = p; p += (size_t)4 * 4 * 64;
  float* vemb  = p; p += (size_t)Bg * 256;

  k_prep<<<(4 * 64 * QW2 + 255) / 256, 256, 0, stream>>>(Wq, bq, Wk, bk, Wv, bv, We, be,
                                                         Wskip, bskip, W_edge, b_edge,
                                                         Wcat, bcat);
  k_prep2<<<36, 256, 0, stream>>>(We, be, W_edge, b_edge, Gbuf, bbuf);
  k_node_enc<<<Nn * 64 / 256, 256, 0, stream>>>(x, W_node, b_node, hbuf);

  for (int i = 0; i < 4; ++i) {
    k_qkv<<<dim3(4, Nn / 16), 256, 0, stream>>>(hbuf, Wcat + (size_t)i * 64 * QWP2,
                                                bcat + i * QW2, qkvr);
    k_attn<<<dim3(Bg, 4), 512, 0, stream>>>(qkvr, edge_attr, ei, sbuf);
    k_update<<<Nn * 64 / 256, 256, 0, stream>>>(qkvr, sbuf, Gbuf + i * 2048,
                                                bbuf + i * 256, hbuf, vemb, i);
  }
  k_head<<<Bg, 64, 0, stream>>>(vemb, W_down, b_down, W_out, b_out, out);
}

// Round 10
// 933.486 us; speedup vs baseline: 6.5891x; 1.1223x over previous
//
#include <hip/hip_runtime.h>
#include <hip/hip_bf16.h>

constexpr int Nn  = 32768;   // total nodes
constexpr int Ej  = 294912;  // total edges
constexpr int Bg  = 256;     // graphs
constexpr int EPG = 1152;    // edges per graph
constexpr int QW2  = 868;    // fused row: q256 | k256 | v256 | r8:32 | skip64 | qb4
constexpr int QWP2 = 880;    // padded row stride: 3520 B = 55 * 64 B
constexpr int SP   = 132;    // S/Wmat fp32 LDS row stride (floats)
constexpr int QS   = 80;     // Q/K bf16 LDS row stride (halfwords)
constexpr int VS   = 136;    // Vt/Wbf bf16 LDS row stride (halfwords)

typedef __attribute__((ext_vector_type(8))) short short8;   // 8 bf16 = 4 VGPRs (MFMA A/B frag)
typedef __attribute__((ext_vector_type(4))) float f32x4;    // MFMA C/D frag

// monotone float<->uint encoding for atomicMax on floats
__device__ __forceinline__ unsigned encf(float f) {
  unsigned u = __float_as_uint(f);
  return (u & 0x80000000u) ? ~u : (u | 0x80000000u);
}
__device__ __forceinline__ float decf(unsigned u) {
  return (u & 0x80000000u) ? __uint_as_float(u & 0x7FFFFFFFu) : __uint_as_float(~u);
}
// fp32 -> bf16 bits, round-to-nearest-even
__device__ __forceinline__ unsigned short f2bf(float f) {
  unsigned u = __float_as_uint(f);
  u += 0x7FFFu + ((u >> 16) & 1u);
  return (unsigned short)(u >> 16);
}
// 64-lane sum via DPP. Result valid in lane 63.
__device__ __forceinline__ float wave_red_sum(float x) {
  x += __int_as_float(__builtin_amdgcn_update_dpp(0, __float_as_int(x), 0x111, 0xf, 0xf, true));
  x += __int_as_float(__builtin_amdgcn_update_dpp(0, __float_as_int(x), 0x112, 0xf, 0xf, true));
  x += __int_as_float(__builtin_amdgcn_update_dpp(0, __float_as_int(x), 0x114, 0xf, 0xf, true));
  x += __int_as_float(__builtin_amdgcn_update_dpp(0, __float_as_int(x), 0x118, 0xf, 0xf, true));
  x += __int_as_float(__builtin_amdgcn_update_dpp(0, __float_as_int(x), 0x142, 0xf, 0xf, true));
  x += __int_as_float(__builtin_amdgcn_update_dpp(0, __float_as_int(x), 0x143, 0xf, 0xf, true));
  return x;
}

// h[n,c] = sum_d x[n,d] * Wn[d,c] + bn[c]   (XD=16)
__global__ void k_node_enc(const float* __restrict__ x, const float* __restrict__ W,
                           const float* __restrict__ b, float* __restrict__ h) {
  int tid = blockIdx.x * 256 + threadIdx.x;  // Nn*64
  int n = tid >> 6, c = tid & 63;
  float acc = b[c];
#pragma unroll
  for (int d = 0; d < 16; ++d)
    acc += x[n * 16 + d] * W[d * 64 + c];
  h[tid] = acc;
}

// G[l][h][a][c] = sum_d W_edge[a,d]*We_l[d][h64+c];  bb[l][h][c] = be + b_edge@We
// (feeds k_update only)
__global__ void k_prep2(const float* __restrict__ We, const float* __restrict__ be,
                        const float* __restrict__ W_edge, const float* __restrict__ b_edge,
                        float* __restrict__ G, float* __restrict__ bb) {
  int tid = blockIdx.x * 256 + threadIdx.x;  // 8192 + 1024
  if (tid < 8192) {
    int l = tid >> 11, rem = tid & 2047;
    int hh = rem >> 9, a = (rem >> 6) & 7, c = rem & 63;
    float acc = 0.f;
#pragma unroll 8
    for (int d = 0; d < 64; ++d)
      acc += W_edge[a * 64 + d] * We[l * 16384 + d * 256 + hh * 64 + c];
    G[tid] = acc;
  } else if (tid < 9216) {
    int t = tid - 8192;
    int l = t >> 8, rem = t & 255;
    int hh = rem >> 6, c = rem & 63;
    float acc = be[l * 256 + hh * 64 + c];
#pragma unroll 8
    for (int d = 0; d < 64; ++d)
      acc += b_edge[d] * We[l * 16384 + d * 256 + hh * 64 + c];
    bb[t] = acc;
  }
}

// Light columns of Wcat/bcat: pure copies (+0.125 on q). Reads d_in only.
__global__ void k_prep_light(const float* __restrict__ Wq, const float* __restrict__ bq,
                             const float* __restrict__ Wk, const float* __restrict__ bk,
                             const float* __restrict__ Wv, const float* __restrict__ bv,
                             const float* __restrict__ Wskip, const float* __restrict__ bskip,
                             float* __restrict__ Wcat, float* __restrict__ bcat) {
  int tid = blockIdx.x * 256 + threadIdx.x;  // 4*64*QW2
  if (tid >= 4 * 64 * QW2) return;
  int l = tid / (64 * QW2);
  int rem = tid % (64 * QW2);
  int k = rem / QW2, col = rem % QW2;
  float w, bias;
  if (col < 256) {
    w = 0.125f * Wq[l * 16384 + k * 256 + col]; bias = 0.125f * bq[l * 256 + col];
  } else if (col < 512) {
    int j = col - 256; w = Wk[l * 16384 + k * 256 + j]; bias = bk[l * 256 + j];
  } else if (col < 768) {
    int j = col - 512; w = Wv[l * 16384 + k * 256 + j]; bias = bv[l * 256 + j];
  } else if (col >= 800 && col < 864) {
    int j = col - 800; w = Wskip[l * 4096 + k * 64 + j]; bias = bskip[l * 64 + j];
  } else {
    return;  // heavy cols [768,800) and [864,868) owned by k_prep_heavy
  }
  Wcat[(size_t)l * 64 * QWP2 + k * QWP2 + col] = w;
  if (k == 0) bcat[l * QW2 + col] = bias;
}

// Heavy columns: one WAVE per element. Reads d_in only (no intermediate deps).
// eid in [0,9216): l = eid/2304; k = (eid%2304)/36; j = eid%36.
//   j<32: r8 col (hh=j>>3, a=j&7): w = 0.125*sum_c Wq[k,hh64+c] * (sum_d We[d,hh64+c]*W_edge[a,d])
//   j>=32: qb' col (hh=j-32):      w = 0.125*sum_c Wq[k,hh64+c] * (be[hh64+c] + sum_d b_edge[d]*We[d,hh64+c])
// bias: same with bq (written when k==0).
__global__ void __launch_bounds__(256) k_prep_heavy(
    const float* __restrict__ Wq, const float* __restrict__ bq,
    const float* __restrict__ We, const float* __restrict__ be,
    const float* __restrict__ W_edge, const float* __restrict__ b_edge,
    float* __restrict__ Wcat, float* __restrict__ bcat) {
  int eid = blockIdx.x * 4 + (threadIdx.x >> 6);  // 2304 blocks * 4 waves
  int lane = threadIdx.x & 63;
  int l = eid / 2304;
  int rem = eid % 2304;
  int k = rem / 36, j = rem % 36;
  int hh, col;
  float inner;
  const float* We_l = We + l * 16384;
  if (j < 32) {
    hh = j >> 3;
    int a = j & 7;
    col = 768 + j;
    float s = 0.f;
#pragma unroll 8
    for (int d = 0; d < 64; ++d)
      s += We_l[d * 256 + hh * 64 + lane] * W_edge[a * 64 + d];
    inner = s;
  } else {
    hh = j - 32;
    col = 864 + hh;
    float s = be[l * 256 + hh * 64 + lane];
#pragma unroll 8
    for (int d = 0; d < 64; ++d)
      s += b_edge[d] * We_l[d * 256 + hh * 64 + lane];
    inner = s;
  }
  float w = Wq[l * 16384 + k * 256 + hh * 64 + lane] * inner;
  float b2 = bq[l * 256 + hh * 64 + lane] * inner;
  float sw = wave_red_sum(w);
  float sb = wave_red_sum(b2);
  if (lane == 63) {
    Wcat[(size_t)l * 64 * QWP2 + k * QWP2 + col] = 0.125f * sw;
    if (k == 0) bcat[l * QW2 + col] = 0.125f * sb;
  }
}

// Fused node GEMM: out[n, 0..QW2) = h[n,:] @ Wcat_l + bcat_l   (row stride QWP2)
__global__ void __launch_bounds__(256) k_qkv(const float* __restrict__ h,
                                             const float* __restrict__ Wcat_l,
                                             const float* __restrict__ bcat_l,
                                             float* __restrict__ out) {
  __shared__ float hL[16 * 64];
  int tid = threadIdx.x;
  int n0 = blockIdx.y * 16;
  {
    int n = tid >> 4, c4 = tid & 15;
    *(float4*)&hL[n * 64 + c4 * 4] = *(const float4*)&h[(size_t)(n0 + n) * 64 + c4 * 4];
  }
  __syncthreads();
  int jg = tid & 63, ng = tid >> 6;
  int j4 = blockIdx.x * 256 + jg * 4;
  if (j4 >= QW2) return;
  float4 acc0 = {0, 0, 0, 0}, acc1 = {0, 0, 0, 0}, acc2 = {0, 0, 0, 0}, acc3 = {0, 0, 0, 0};
#pragma unroll
  for (int c4 = 0; c4 < 16; ++c4) {
    float4 h0 = *(const float4*)&hL[(ng * 4 + 0) * 64 + c4 * 4];
    float4 h1 = *(const float4*)&hL[(ng * 4 + 1) * 64 + c4 * 4];
    float4 h2 = *(const float4*)&hL[(ng * 4 + 2) * 64 + c4 * 4];
    float4 h3 = *(const float4*)&hL[(ng * 4 + 3) * 64 + c4 * 4];
    const float* hv0 = (const float*)&h0;
    const float* hv1 = (const float*)&h1;
    const float* hv2 = (const float*)&h2;
    const float* hv3 = (const float*)&h3;
#pragma unroll
    for (int cc = 0; cc < 4; ++cc) {
      float4 w = *(const float4*)&Wcat_l[(size_t)(c4 * 4 + cc) * QWP2 + j4];
      acc0.x += hv0[cc] * w.x; acc0.y += hv0[cc] * w.y; acc0.z += hv0[cc] * w.z; acc0.w += hv0[cc] * w.w;
      acc1.x += hv1[cc] * w.x; acc1.y += hv1[cc] * w.y; acc1.z += hv1[cc] * w.z; acc1.w += hv1[cc] * w.w;
      acc2.x += hv2[cc] * w.x; acc2.y += hv2[cc] * w.y; acc2.z += hv2[cc] * w.z; acc2.w += hv2[cc] * w.w;
      acc3.x += hv3[cc] * w.x; acc3.y += hv3[cc] * w.y; acc3.z += hv3[cc] * w.z; acc3.w += hv3[cc] * w.w;
    }
  }
  float4 bb = *(const float4*)&bcat_l[j4];
  acc0.x += bb.x; acc0.y += bb.y; acc0.z += bb.z; acc0.w += bb.w;
  acc1.x += bb.x; acc1.y += bb.y; acc1.z += bb.z; acc1.w += bb.w;
  acc2.x += bb.x; acc2.y += bb.y; acc2.z += bb.z; acc2.w += bb.w;
  acc3.x += bb.x; acc3.y += bb.y; acc3.z += bb.z; acc3.w += bb.w;
  *(float4*)&out[(size_t)(n0 + ng * 4 + 0) * QWP2 + j4] = acc0;
  *(float4*)&out[(size_t)(n0 + ng * 4 + 1) * QWP2 + j4] = acc1;
  *(float4*)&out[(size_t)(n0 + ng * 4 + 2) * QWP2 + j4] = acc2;
  *(float4*)&out[(size_t)(n0 + ng * 4 + 3) * QWP2 + j4] = acc3;
}

// MFMA dense attention. Block = (g,h), 512 threads (8 waves), 128.0 KB LDS.
__global__ void __launch_bounds__(512) k_attn(float* __restrict__ qkvr,
                                              const float* __restrict__ edge_attr,
                                              const int* __restrict__ ei,
                                              float* __restrict__ sbuf) {
  __shared__ unsigned short Qu[128 * QS];   // Q bf16, stride 80
  __shared__ unsigned short KVu[128 * QS];  // P1: K bf16 (stride 80); P2+: Vt bf16 (64 x stride 136)
  __shared__ float S[128 * SP];             // fp32 scores -> Wmat fp32 -> (low) Wmat bf16
  __shared__ float alphaL[EPG];
  __shared__ int edL[EPG];                  // src | dst<<16
  __shared__ float r8L[128 * 8];
  __shared__ float t8L[128 * 9];            // stride 9: spread atomic banks
  __shared__ unsigned mL[128];
  __shared__ float sL[128], qbL[128];
  int g = blockIdx.x, h = blockIdx.y;
  int tid = threadIdx.x;
  int lane = tid & 63, m16 = lane & 15, quad = lane >> 4, wv = tid >> 6;
  float* base = qkvr + (size_t)g * 128 * QWP2;
  const float* eaG = edge_attr + (size_t)g * EPG * 8;

  // ---- P0: stage Q,K as bf16; r8, qb, edges; zero m/s/t8
  for (int idx = tid; idx < 1024; idx += 512) {
    int n = idx >> 3, c8 = idx & 7;
    const float* row = base + n * QWP2 + h * 64 + c8 * 8;
    float4 a0 = *(const float4*)(row), a1 = *(const float4*)(row + 4);
    uint4 qp;
    qp.x = f2bf(a0.x) | ((unsigned)f2bf(a0.y) << 16);
    qp.y = f2bf(a0.z) | ((unsigned)f2bf(a0.w) << 16);
    qp.z = f2bf(a1.x) | ((unsigned)f2bf(a1.y) << 16);
    qp.w = f2bf(a1.z) | ((unsigned)f2bf(a1.w) << 16);
    *(uint4*)&Qu[n * QS + c8 * 8] = qp;
    float4 b0 = *(const float4*)(row + 256), b1 = *(const float4*)(row + 260);
    uint4 kp;
    kp.x = f2bf(b0.x) | ((unsigned)f2bf(b0.y) << 16);
    kp.y = f2bf(b0.z) | ((unsigned)f2bf(b0.w) << 16);
    kp.z = f2bf(b1.x) | ((unsigned)f2bf(b1.y) << 16);
    kp.w = f2bf(b1.z) | ((unsigned)f2bf(b1.w) << 16);
    *(uint4*)&KVu[n * QS + c8 * 8] = kp;
  }
  for (int idx = tid; idx < 256; idx += 512) {
    int n = idx >> 1, pp = idx & 1;
    *(float4*)&r8L[n * 8 + pp * 4] = *(const float4*)(base + n * QWP2 + 768 + h * 8 + pp * 4);
  }
  if (tid < 128) {
    qbL[tid] = base[tid * QWP2 + 864 + h];
    mL[tid] = 0u;
    sL[tid] = 0.f;
  }
  for (int idx = tid; idx < EPG; idx += 512) {
    t8L[idx] = 0.f;
    int s = ei[g * EPG + idx] - g * 128;
    int d = ei[Ej + g * EPG + idx] - g * 128;
    edL[idx] = s | (d << 16);
  }
  __syncthreads();

  // ---- P1: S = Q@K^T.  Wave wv: dst-strip wv*16, all 8 src tiles. K=64 -> 2 mfma/tile.
  {
    int dst0 = wv * 16;
    const short8 a0 = *(const short8*)&Qu[(dst0 + m16) * QS + quad * 8];
    const short8 a1 = *(const short8*)&Qu[(dst0 + m16) * QS + 32 + quad * 8];
#pragma unroll
    for (int st = 0; st < 8; ++st) {
      int src0 = st * 16;
      const short8 b0 = *(const short8*)&KVu[(src0 + m16) * QS + quad * 8];
      const short8 b1 = *(const short8*)&KVu[(src0 + m16) * QS + 32 + quad * 8];
      f32x4 acc = {0.f, 0.f, 0.f, 0.f};
      acc = __builtin_amdgcn_mfma_f32_16x16x32_bf16(a0, b0, acc, 0, 0, 0);
      acc = __builtin_amdgcn_mfma_f32_16x16x32_bf16(a1, b1, acc, 0, 0, 0);
#pragma unroll
      for (int r = 0; r < 4; ++r)
        S[(dst0 + quad * 4 + r) * SP + src0 + m16] = acc[r];
    }
  }
  __syncthreads();

  // ---- P2: stage Vt (bf16, transposed, stride VS); per-edge alpha; segment max
  for (int idx = tid; idx < 1024; idx += 512) {
    int n = idx >> 3, c8 = idx & 7;
    const float* row = base + n * QWP2 + 512 + h * 64 + c8 * 8;
    float4 v0 = *(const float4*)(row), v1 = *(const float4*)(row + 4);
    KVu[(c8 * 8 + 0) * VS + n] = f2bf(v0.x);
    KVu[(c8 * 8 + 1) * VS + n] = f2bf(v0.y);
    KVu[(c8 * 8 + 2) * VS + n] = f2bf(v0.z);
    KVu[(c8 * 8 + 3) * VS + n] = f2bf(v0.w);
    KVu[(c8 * 8 + 4) * VS + n] = f2bf(v1.x);
    KVu[(c8 * 8 + 5) * VS + n] = f2bf(v1.y);
    KVu[(c8 * 8 + 6) * VS + n] = f2bf(v1.z);
    KVu[(c8 * 8 + 7) * VS + n] = f2bf(v1.w);
  }
  for (int e = tid; e < EPG; e += 512) {
    int ed = edL[e];
    int src = ed & 0xffff, dst = ed >> 16;
    float4 ea0 = *(const float4*)(eaG + (size_t)e * 8);
    float4 ea1 = *(const float4*)(eaG + (size_t)e * 8 + 4);
    float4 r80 = *(const float4*)&r8L[dst * 8];
    float4 r81 = *(const float4*)&r8L[dst * 8 + 4];
    float a = S[dst * SP + src] + qbL[dst]
            + ea0.x * r80.x + ea0.y * r80.y + ea0.z * r80.z + ea0.w * r80.w
            + ea1.x * r81.x + ea1.y * r81.y + ea1.z * r81.z + ea1.w * r81.w;
    alphaL[e] = a;
    atomicMax(&mL[dst], encf(a));
  }
  __syncthreads();

  // ---- P3: zero S (whole buffer); exp + segment sum
  for (int idx = tid; idx < 128 * (SP / 4); idx += 512)
    *(float4*)&S[idx * 4] = make_float4(0.f, 0.f, 0.f, 0.f);
  for (int e = tid; e < EPG; e += 512) {
    int dst = edL[e] >> 16;
    float ex = expf(alphaL[e] - decf(mL[dst]));
    alphaL[e] = ex;
    atomicAdd(&sL[dst], ex);
  }
  __syncthreads();

  // ---- P4: scatter normalized weights into Wmat(fp32); accumulate t8 (stride 9)
  for (int e = tid; e < EPG; e += 512) {
    int ed = edL[e];
    int src = ed & 0xffff, dst = ed >> 16;
    float w = alphaL[e] / fmaxf(sL[dst], 1e-16f);
    atomicAdd(&S[dst * SP + src], w);
    float4 ea0 = *(const float4*)(eaG + (size_t)e * 8);
    float4 ea1 = *(const float4*)(eaG + (size_t)e * 8 + 4);
    float* t8 = &t8L[dst * 9];
    atomicAdd(t8 + 0, w * ea0.x); atomicAdd(t8 + 1, w * ea0.y);
    atomicAdd(t8 + 2, w * ea0.z); atomicAdd(t8 + 3, w * ea0.w);
    atomicAdd(t8 + 4, w * ea1.x); atomicAdd(t8 + 5, w * ea1.y);
    atomicAdd(t8 + 6, w * ea1.z); atomicAdd(t8 + 7, w * ea1.w);
  }
  __syncthreads();

  // ---- P4.5: repack Wmat fp32 -> bf16 in place (stride VS), regs + barrier
  {
    float vals[32];
    int i0 = tid * 32;
    int dst = i0 >> 7, src0 = i0 & 127;
#pragma unroll
    for (int i = 0; i < 32; ++i)
      vals[i] = S[dst * SP + src0 + i];
    __syncthreads();
    unsigned short* Wu = (unsigned short*)S;
#pragma unroll
    for (int g4 = 0; g4 < 4; ++g4) {
      uint4 u;
      u.x = f2bf(vals[g4 * 8 + 0]) | ((unsigned)f2bf(vals[g4 * 8 + 1]) << 16);
      u.y = f2bf(vals[g4 * 8 + 2]) | ((unsigned)f2bf(vals[g4 * 8 + 3]) << 16);
      u.z = f2bf(vals[g4 * 8 + 4]) | ((unsigned)f2bf(vals[g4 * 8 + 5]) << 16);
      u.w = f2bf(vals[g4 * 8 + 6]) | ((unsigned)f2bf(vals[g4 * 8 + 7]) << 16);
      *(uint4*)&Wu[dst * VS + src0 + g4 * 8] = u;
    }
  }
  __syncthreads();

  // ---- P5: agg = Wmat(128x128)@V(128x64) via MFMA. Wave wv: dst-strip, 4 c-tiles.
  {
    const unsigned short* Wu = (const unsigned short*)S;
    int dst0 = wv * 16;
    short8 a[4];
#pragma unroll
    for (int ks = 0; ks < 4; ++ks)
      a[ks] = *(const short8*)&Wu[(dst0 + m16) * VS + ks * 32 + quad * 8];
#pragma unroll
    for (int ct = 0; ct < 4; ++ct) {
      int c0 = ct * 16;
      f32x4 acc = {0.f, 0.f, 0.f, 0.f};
#pragma unroll
      for (int ks = 0; ks < 4; ++ks) {
        const short8 b = *(const short8*)&KVu[(c0 + m16) * VS + ks * 32 + quad * 8];
        acc = __builtin_amdgcn_mfma_f32_16x16x32_bf16(a[ks], b, acc, 0, 0, 0);
      }
#pragma unroll
      for (int r = 0; r < 4; ++r)
        base[(size_t)(dst0 + quad * 4 + r) * QWP2 + h * 64 + c0 + m16] = acc[r];
    }
  }
  // t8 + s writeback
  if (tid < 128) {
    float tmp[8];
#pragma unroll
    for (int j = 0; j < 8; ++j) tmp[j] = t8L[tid * 9 + j];
    *(float4*)(base + tid * QWP2 + 768 + h * 8) = make_float4(tmp[0], tmp[1], tmp[2], tmp[3]);
    *(float4*)(base + tid * QWP2 + 768 + h * 8 + 4) = make_float4(tmp[4], tmp[5], tmp[6], tmp[7]);
    sbuf[(g * 128 + tid) * 4 + h] = sL[tid];
  }
}

// out[n,c] = 0.25*sum_h( aggv + t8@G_h + (s>0)*bb_h ) + sk; stash virtual rows; h += out
__global__ void k_update(const float* __restrict__ qkvr, const float* __restrict__ s,
                         const float* __restrict__ G_l, const float* __restrict__ bb_l,
                         float* h, float* __restrict__ vemb, int layer) {
  int tid = blockIdx.x * 256 + threadIdx.x;  // Nn*64
  int n = tid >> 6, c = tid & 63;
  const float* row = qkvr + (size_t)n * QWP2;
  float acc = 0.f;
#pragma unroll
  for (int hh = 0; hh < 4; ++hh) {
    float sw = (s[n * 4 + hh] > 0.f) ? 1.f : 0.f;
    float a = row[hh * 64 + c] + sw * bb_l[hh * 64 + c];
#pragma unroll
    for (int a8 = 0; a8 < 8; ++a8)
      a += row[768 + hh * 8 + a8] * G_l[(hh * 8 + a8) * 64 + c];
    acc += a;
  }
  float outv = acc * 0.25f + row[800 + c];
  if ((n & 127) == 127)
    vemb[(n >> 7) * 256 + layer * 64 + c] = outv;
  h[tid] = outv + h[tid];
}

// pool = vemb @ W_down + b_down; out = sigmoid(pool @ W_out + b_out)
__global__ void k_head(const float* __restrict__ vemb, const float* __restrict__ Wd,
                       const float* __restrict__ bd, const float* __restrict__ Wo,
                       const float* __restrict__ bo, float* __restrict__ out) {
  int g = blockIdx.x;
  int c = threadIdx.x;  // 64 threads
  const float* vr = vemb + g * 256;
  float acc = bd[c];
#pragma unroll 16
  for (int j = 0; j < 256; ++j)
    acc += vr[j] * Wd[j * 64 + c];
  float p = acc * Wo[c];
#pragma unroll
  for (int off = 32; off; off >>= 1) p += __shfl_down(p, off);
  if (c == 0) {
    float logit = p + bo[0];
    out[g] = 1.f / (1.f + expf(-logit));
  }
}

extern "C" void kernel_launch(void* const* d_in, const int* in_sizes, int n_in,
                              void* d_out, int out_size, void* d_ws, size_t ws_size,
                              hipStream_t stream) {
  const float* x         = (const float*)d_in[0];
  const float* edge_attr = (const float*)d_in[1];
  const int*   ei        = (const int*)d_in[2];
  const float* W_node = (const float*)d_in[4];
  const float* b_node = (const float*)d_in[5];
  const float* W_edge = (const float*)d_in[6];
  const float* b_edge = (const float*)d_in[7];
  const float* Wq = (const float*)d_in[8];
  const float* bq = (const float*)d_in[9];
  const float* Wk = (const float*)d_in[10];
  const float* bk = (const float*)d_in[11];
  const float* Wv = (const float*)d_in[12];
  const float* bv = (const float*)d_in[13];
  const float* We = (const float*)d_in[14];
  const float* be = (const float*)d_in[15];
  const float* Wskip = (const float*)d_in[16];
  const float* bskip = (const float*)d_in[17];
  const float* W_down = (const float*)d_in[18];
  const float* b_down = (const float*)d_in[19];
  const float* W_out  = (const float*)d_in[20];
  const float* b_out  = (const float*)d_in[21];
  float* out = (float*)d_out;

  // workspace carve (fp32): ~125 MiB total
  float* p = (float*)d_ws;
  float* hbuf  = p; p += (size_t)Nn * 64;        //   8.4 MB
  float* qkvr  = p; p += (size_t)Nn * QWP2;      // 115.3 MB
  float* sbuf  = p; p += (size_t)Nn * 4;
  float* Wcat  = p; p += (size_t)4 * 64 * QWP2;
  float* bcat  = p; p += (size_t)4 * QW2;
  float* Gbuf  = p; p += (size_t)4 * 4 * 8 * 64;
  float* bbuf  = p; p += (size_t)4 * 4 * 64;
  float* vemb  = p; p += (size_t)Bg * 256;

  k_prep2<<<36, 256, 0, stream>>>(We, be, W_edge, b_edge, Gbuf, bbuf);
  k_prep_light<<<(4 * 64 * QW2 + 255) / 256, 256, 0, stream>>>(Wq, bq, Wk, bk, Wv, bv,
                                                               Wskip, bskip, Wcat, bcat);
  k_prep_heavy<<<2304, 256, 0, stream>>>(Wq, bq, We, be, W_edge, b_edge, Wcat, bcat);
  k_node_enc<<<Nn * 64 / 256, 256, 0, stream>>>(x, W_node, b_node, hbuf);

  for (int i = 0; i < 4; ++i) {
    k_qkv<<<dim3(4, Nn / 16), 256, 0, stream>>>(hbuf, Wcat + (size_t)i * 64 * QWP2,
                                                bcat + i * QW2, qkvr);
    k_attn<<<dim3(Bg, 4), 512, 0, stream>>>(qkvr, edge_attr, ei, sbuf);
    k_update<<<Nn * 64 / 256, 256, 0, stream>>>(qkvr, sbuf, Gbuf + i * 2048,
                                                bbuf + i * 256, hbuf, vemb, i);
  }
  k_head<<<Bg, 64, 0, stream>>>(vemb, W_down, b_down, W_out, b_out, out);
}